// Round 1
// baseline (2729.648 us; speedup 1.0000x reference)
//
#include <hip/hip_runtime.h>
#include <math.h>

// Problem constants
#define BB 2
#define TT 4
#define CIN 128
#define HH 64
#define WW 64
#define DM 256
#define NQ 300
#define NP 8
#define PS 3
#define NL 6
#define HW 4096   // 64*64

// ---------------------------------------------------------------------------
// K1: temporal conv (k=3, pad 1 on T) + mean over T, fused via per-u coeffs.
// out tmean (B, CIN, 64, 64) channel-first. Block: 256 threads over spatial,
// 2 output channels per block (weights uniform -> scalar loads).
// grid = B * (CIN/2) * 16
__global__ __launch_bounds__(256) void k_tmean(const float* __restrict__ feat,
                                               const float* __restrict__ w_tf,
                                               const float* __restrict__ b_tf,
                                               float* __restrict__ tmean) {
  int bi = blockIdx.x;
  int tileS = bi & 15;
  int cg = (bi >> 4) & 63;
  int b = bi >> 10;
  int c0 = cg * 2;
  int s = tileS * 256 + threadIdx.x;
  float acc0 = 0.f, acc1 = 0.f;
  const float* fb = feat + (size_t)b * TT * CIN * HW;
  for (int ci = 0; ci < CIN; ++ci) {
    float f0 = fb[(0 * CIN + ci) * HW + s];
    float f1 = fb[(1 * CIN + ci) * HW + s];
    float f2 = fb[(2 * CIN + ci) * HW + s];
    float f3 = fb[(3 * CIN + ci) * HW + s];
    float f12 = f1 + f2;
    {
      const float* wp = w_tf + ((size_t)(c0 + 0) * CIN + ci) * 3;
      float w0 = wp[0], w1 = wp[1], w2 = wp[2];
      acc0 += f0 * (w0 + w1) + f12 * (w0 + w1 + w2) + f3 * (w1 + w2);
    }
    {
      const float* wp = w_tf + ((size_t)(c0 + 1) * CIN + ci) * 3;
      float w0 = wp[0], w1 = wp[1], w2 = wp[2];
      acc1 += f0 * (w0 + w1) + f12 * (w0 + w1 + w2) + f3 * (w1 + w2);
    }
  }
  tmean[((size_t)b * CIN + c0 + 0) * HW + s] = acc0 * 0.25f + b_tf[c0 + 0];
  tmean[((size_t)b * CIN + c0 + 1) * HW + s] = acc1 * 0.25f + b_tf[c0 + 1];
}

// ---------------------------------------------------------------------------
// K2: input projection (128->256, 1x1) + bias + sine positional encoding.
// 4 output channels per block. grid = B * (DM/4) * 16
__global__ __launch_bounds__(256) void k_proj(const float* __restrict__ tmean,
                                              const float* __restrict__ w_in,
                                              const float* __restrict__ b_in,
                                              float* __restrict__ x) {
  int bi = blockIdx.x;
  int tileS = bi & 15;
  int dg = (bi >> 4) & 63;
  int b = bi >> 10;
  int d0 = dg * 4;
  int s = tileS * 256 + threadIdx.x;
  float acc[4] = {0.f, 0.f, 0.f, 0.f};
  const float* tb = tmean + (size_t)b * CIN * HW;
  for (int c = 0; c < CIN; ++c) {
    float t = tb[c * HW + s];
    acc[0] += t * w_in[(d0 + 0) * CIN + c];
    acc[1] += t * w_in[(d0 + 1) * CIN + c];
    acc[2] += t * w_in[(d0 + 2) * CIN + c];
    acc[3] += t * w_in[(d0 + 3) * CIN + c];
  }
  int h = s >> 6, w = s & 63;
  const float TWO_PI = 6.28318530717958647692f;
  float yn = (float)(h + 1) / (64.0f + 1e-6f) * TWO_PI;
  float xn = (float)(w + 1) / (64.0f + 1e-6f) * TWO_PI;
#pragma unroll
  for (int j = 0; j < 4; ++j) {
    int d = d0 + j;
    int dd = (d < 128) ? d : (d - 128);
    int ii = dd >> 1;
    float e = (2.0f * (float)(ii >> 1)) / 64.0f;
    float dimt = powf(10000.0f, e);
    float ang = ((d < 128) ? yn : xn) / dimt;
    float pos = (dd & 1) ? cosf(ang) : sinf(ang);
    x[((size_t)b * DM + d) * HW + s] = acc[j] + b_in[d] + pos;
  }
}

// ---------------------------------------------------------------------------
// K3: lateral 1x1 conv (256->256), scale 0 only. grid = B * (DM/4) * 16
__global__ __launch_bounds__(256) void k_lat(const float* __restrict__ x,
                                             const float* __restrict__ wl,
                                             const float* __restrict__ bl,
                                             float* __restrict__ x2) {
  int bi = blockIdx.x;
  int tileS = bi & 15;
  int og = (bi >> 4) & 63;
  int b = bi >> 10;
  int o0 = og * 4;
  int s = tileS * 256 + threadIdx.x;
  float acc[4] = {0.f, 0.f, 0.f, 0.f};
  const float* xb = x + (size_t)b * DM * HW;
  for (int c = 0; c < DM; ++c) {
    float t = xb[c * HW + s];
    acc[0] += t * wl[(o0 + 0) * DM + c];
    acc[1] += t * wl[(o0 + 1) * DM + c];
    acc[2] += t * wl[(o0 + 2) * DM + c];
    acc[3] += t * wl[(o0 + 3) * DM + c];
  }
#pragma unroll
  for (int j = 0; j < 4; ++j)
    x2[((size_t)b * DM + o0 + j) * HW + s] = acc[j] + bl[o0 + j];
}

// ---------------------------------------------------------------------------
// K4: 3x3 smooth conv (256->256, pad 1), writes CHANNEL-LAST (B,64,64,256).
// Block: 16x16 spatial tile, 4 output channels; stages 4 input channels of
// 18x18 halo tile in LDS per chunk. grid = B * (DM/4) * 16
__global__ __launch_bounds__(256) void k_smooth(const float* __restrict__ x2,
                                                const float* __restrict__ wsm,
                                                const float* __restrict__ bsm,
                                                float* __restrict__ fcl) {
  __shared__ float tile[4][18 * 18];
  int bi = blockIdx.x;
  int t16 = bi & 15;
  int og = (bi >> 4) & 63;
  int b = bi >> 10;
  int o0 = og * 4;
  int ty0 = (t16 >> 2) * 16, tx0 = (t16 & 3) * 16;
  int tid = threadIdx.x;
  int ly = tid >> 4, lx = tid & 15;
  float acc[4] = {0.f, 0.f, 0.f, 0.f};
  for (int c0 = 0; c0 < DM; c0 += 4) {
    __syncthreads();
    for (int idx = tid; idx < 4 * 324; idx += 256) {
      int cc = idx / 324;
      int r = idx - cc * 324;
      int gy = ty0 - 1 + r / 18;
      int gx = tx0 - 1 + r % 18;
      float v = 0.f;
      if (gy >= 0 && gy < 64 && gx >= 0 && gx < 64)
        v = x2[((size_t)b * DM + c0 + cc) * HW + gy * 64 + gx];
      tile[cc][r] = v;
    }
    __syncthreads();
#pragma unroll
    for (int cc = 0; cc < 4; ++cc) {
      int c = c0 + cc;
      float v[9];
#pragma unroll
      for (int ky = 0; ky < 3; ++ky)
#pragma unroll
        for (int kx = 0; kx < 3; ++kx)
          v[ky * 3 + kx] = tile[cc][(ly + ky) * 18 + lx + kx];
#pragma unroll
      for (int j = 0; j < 4; ++j) {
        const float* wp = wsm + ((size_t)(o0 + j) * DM + c) * 9;
#pragma unroll
        for (int t = 0; t < 9; ++t) acc[j] += v[t] * wp[t];
      }
    }
  }
  int y = ty0 + ly, xx = tx0 + lx;
#pragma unroll
  for (int j = 0; j < 4; ++j)
    fcl[((size_t)b * HW + y * 64 + xx) * DM + o0 + j] = acc[j] + bsm[o0 + j];
}

// ---------------------------------------------------------------------------
// queries = q_embed + q_pos broadcast to both b; boxes init copy.
__global__ void k_init(const float* __restrict__ qe, const float* __restrict__ qp,
                       const float* __restrict__ pb, float* __restrict__ queries,
                       float* __restrict__ boxes) {
  int i = blockIdx.x * 256 + threadIdx.x;
  if (i < BB * NQ * DM) {
    int rd = i % (NQ * DM);
    queries[i] = qe[rd] + qp[rd];
  }
  if (i < BB * NQ * 4) boxes[i] = pb[i];
}

// ---------------------------------------------------------------------------
// Generic GEMM: C[m,n] = act( sum_k A[m,k] * W[n,k] + bias[n] ) (+ res[m,n])
// A (M,K) row-major, W (N,K) row-major (einsum 'md,od->mo' weight layout).
// 64x64x16 tiles, 256 threads, 4x4 per-thread microtile.
template <int ACT, bool RES>
__global__ __launch_bounds__(256) void k_gemm(const float* __restrict__ A,
                                              const float* __restrict__ W,
                                              const float* __restrict__ bias,
                                              const float* __restrict__ res,
                                              float* __restrict__ C,
                                              int M, int N, int K) {
  __shared__ float As[16][64];
  __shared__ float Bs[16][64];
  int tid = threadIdx.x;
  int bm = blockIdx.x * 64;
  int bn = blockIdx.y * 64;
  int tx = tid & 15, ty = tid >> 4;
  int lr = tid >> 2;
  int lc = (tid & 3) << 2;
  float acc[4][4] = {};
  for (int k0 = 0; k0 < K; k0 += 16) {
    int gm = bm + lr;
    float4 av = make_float4(0.f, 0.f, 0.f, 0.f);
    if (gm < M) av = *(const float4*)(A + (size_t)gm * K + k0 + lc);
    As[lc + 0][lr] = av.x; As[lc + 1][lr] = av.y;
    As[lc + 2][lr] = av.z; As[lc + 3][lr] = av.w;
    int gn = bn + lr;
    float4 bv = make_float4(0.f, 0.f, 0.f, 0.f);
    if (gn < N) bv = *(const float4*)(W + (size_t)gn * K + k0 + lc);
    Bs[lc + 0][lr] = bv.x; Bs[lc + 1][lr] = bv.y;
    Bs[lc + 2][lr] = bv.z; Bs[lc + 3][lr] = bv.w;
    __syncthreads();
#pragma unroll
    for (int kk = 0; kk < 16; ++kk) {
      float4 a4 = *(const float4*)&As[kk][ty * 4];
      float4 b4 = *(const float4*)&Bs[kk][tx * 4];
      float a[4] = {a4.x, a4.y, a4.z, a4.w};
      float bb4[4] = {b4.x, b4.y, b4.z, b4.w};
#pragma unroll
      for (int i = 0; i < 4; ++i)
#pragma unroll
        for (int j = 0; j < 4; ++j) acc[i][j] += a[i] * bb4[j];
    }
    __syncthreads();
  }
#pragma unroll
  for (int i = 0; i < 4; ++i) {
    int m = bm + ty * 4 + i;
    if (m >= M) continue;
#pragma unroll
    for (int j = 0; j < 4; ++j) {
      int n = bn + tx * 4 + j;
      if (n >= N) continue;
      float v = acc[i][j];
      if (bias) v += bias[n];
      if (ACT == 1) v = fmaxf(v, 0.f);
      if (RES) v += res[(size_t)m * N + n];
      C[(size_t)m * N + n] = v;
    }
  }
}

// ---------------------------------------------------------------------------
// ro = tanh(h1 @ w_r2^T + b_r2)*0.5 ; ref = clip(box_xy + ro, 0, 1)
// one thread per (row, o) with o in [0,16)
__global__ void k_r2ref(const float* __restrict__ h1, const float* __restrict__ w_r2,
                        const float* __restrict__ b_r2, const float* __restrict__ boxes,
                        float* __restrict__ ref) {
  int i = blockIdx.x * 256 + threadIdx.x;
  if (i >= BB * NQ * 2 * NP) return;
  int row = i >> 4, o = i & 15;
  const float* hp = h1 + (size_t)row * DM;
  const float* wp = w_r2 + (size_t)o * DM;
  float acc = b_r2[o];
  for (int k = 0; k < DM; ++k) acc += hp[k] * wp[k];
  float ro = 0.5f * tanhf(acc);
  int ax = o & 1;
  float v = boxes[row * 4 + ax] + ro;
  ref[i] = fminf(fmaxf(v, 0.f), 1.f);
}

// ---------------------------------------------------------------------------
// Bilinear patch sampling from channel-last feat0. Block per (b,q,p), thread=c.
__global__ __launch_bounds__(256) void k_sample(const float* __restrict__ fcl,
                                                const float* __restrict__ ref,
                                                float* __restrict__ flat) {
  int blk = blockIdx.x;             // (b*NQ+q)*NP + p
  int c = threadIdx.x;
  int row = blk >> 3;
  int b = row / NQ;
  float rx = ref[blk * 2 + 0];
  float ry = ref[blk * 2 + 1];
  const float* fb = fcl + (size_t)b * HW * DM;
  float* op = flat + (size_t)blk * (PS * PS * DM);
#pragma unroll
  for (int jy = 0; jy < 3; ++jy) {
    float yy = (ry + (float)(jy - 1) * (1.0f / 64.0f)) * 63.0f;
    yy = fminf(fmaxf(yy, 0.f), 63.0f);
    float y0f = floorf(yy);
    float wy = yy - y0f;
    int y0 = (int)y0f;
    int y1 = min(y0 + 1, 63);
#pragma unroll
    for (int jx = 0; jx < 3; ++jx) {
      float xx = (rx + (float)(jx - 1) * (1.0f / 64.0f)) * 63.0f;
      xx = fminf(fmaxf(xx, 0.f), 63.0f);
      float x0f = floorf(xx);
      float wx = xx - x0f;
      int x0 = (int)x0f;
      int x1 = min(x0 + 1, 63);
      float v00 = fb[(y0 * 64 + x0) * DM + c];
      float v01 = fb[(y0 * 64 + x1) * DM + c];
      float v10 = fb[(y1 * 64 + x0) * DM + c];
      float v11 = fb[(y1 * 64 + x1) * DM + c];
      float v = v00 * (1.f - wx) * (1.f - wy) + v01 * wx * (1.f - wy) +
                v10 * (1.f - wx) * wy + v11 * wx * wy;
      op[(jy * 3 + jx) * DM + c] = v;
    }
  }
}

// ---------------------------------------------------------------------------
// mean over the 8 points: pvm[row,d] = mean_p pv1[row,p,d]
__global__ void k_pmean(const float* __restrict__ pv1, float* __restrict__ pvm) {
  int i = blockIdx.x * 256 + threadIdx.x;
  if (i >= BB * NQ * DM) return;
  int row = i >> 8, d = i & 255;
  float s = 0.f;
#pragma unroll
  for (int p = 0; p < NP; ++p) s += pv1[((size_t)row * NP + p) * DM + d];
  pvm[i] = s * 0.125f;
}

// ---------------------------------------------------------------------------
// attention: one block per (b,q) row. scores over 300 keys, softmax, weighted sum.
__global__ __launch_bounds__(256) void k_attn(const float* __restrict__ qb,
                                              const float* __restrict__ kv,
                                              float* __restrict__ ao) {
  __shared__ float sc[512];
  __shared__ float qs[256];
  __shared__ float red[256];
  int row = blockIdx.x;
  int b = row / NQ;
  int tid = threadIdx.x;
  qs[tid] = qb[(size_t)row * DM + tid];
  __syncthreads();
  const float* kvb = kv + (size_t)b * NQ * DM;
  for (int k = tid; k < 512; k += 256) {
    float v = -1e30f;
    if (k < NQ) {
      const float* kp = kvb + (size_t)k * DM;
      float a = 0.f;
      for (int d = 0; d < DM; ++d) a += qs[d] * kp[d];
      v = a * (1.0f / 16.0f);
    }
    sc[k] = v;
  }
  __syncthreads();
  red[tid] = fmaxf(sc[tid], sc[tid + 256]);
  __syncthreads();
  for (int st = 128; st > 0; st >>= 1) {
    if (tid < st) red[tid] = fmaxf(red[tid], red[tid + st]);
    __syncthreads();
  }
  float mx = red[0];
  __syncthreads();
  float e0 = (tid < NQ) ? expf(sc[tid] - mx) : 0.f;
  float e1 = (tid + 256 < NQ) ? expf(sc[tid + 256] - mx) : 0.f;
  sc[tid] = e0;
  sc[tid + 256] = e1;
  red[tid] = e0 + e1;
  __syncthreads();
  for (int st = 128; st > 0; st >>= 1) {
    if (tid < st) red[tid] += red[tid + st];
    __syncthreads();
  }
  float inv = 1.0f / red[0];
  __syncthreads();
  float acc = 0.f;
  for (int k = 0; k < NQ; ++k) acc += sc[k] * kvb[(size_t)k * DM + tid];
  ao[(size_t)row * DM + tid] = acc * inv;
}

// ---------------------------------------------------------------------------
// box head tail: delta = sigmoid(hb @ w_b2^T + b_b2); boxes update in place.
__global__ void k_box(const float* __restrict__ hb, const float* __restrict__ w_b2,
                      const float* __restrict__ b_b2, float* __restrict__ boxes) {
  int i = blockIdx.x * 256 + threadIdx.x;
  if (i >= BB * NQ * 4) return;
  int row = i >> 2, j = i & 3;
  const float* hp = hb + (size_t)row * DM;
  const float* wp = w_b2 + (size_t)j * DM;
  float a = b_b2[j];
  for (int k = 0; k < DM; ++k) a += hp[k] * wp[k];
  float delta = 1.0f / (1.0f + expf(-a));
  float v = boxes[i] + 0.1f * tanhf(delta - 0.5f);
  boxes[i] = fminf(fmaxf(v, 0.f), 1.f);
}

// ---------------------------------------------------------------------------
// logits + boxes -> d_out. out[0..599]=logits, out[600..2999]=boxes.
__global__ void k_final(const float* __restrict__ queries, const float* __restrict__ w_cls,
                        const float* __restrict__ b_cls, const float* __restrict__ boxes,
                        float* __restrict__ out) {
  int i = blockIdx.x * 256 + threadIdx.x;
  if (i < BB * NQ) {
    const float* qp = queries + (size_t)i * DM;
    float a = b_cls[0];
    for (int k = 0; k < DM; ++k) a += qp[k] * w_cls[k];
    out[i] = a;
  }
  if (i < BB * NQ * 4) out[BB * NQ + i] = boxes[i];
}

// ---------------------------------------------------------------------------
extern "C" void kernel_launch(void* const* d_in, const int* in_sizes, int n_in,
                              void* d_out, int out_size, void* d_ws, size_t ws_size,
                              hipStream_t stream) {
  const float* feat   = (const float*)d_in[0];
  const float* pb     = (const float*)d_in[1];
  const float* w_tf   = (const float*)d_in[2];
  const float* b_tf   = (const float*)d_in[3];
  const float* w_in   = (const float*)d_in[4];
  const float* b_in   = (const float*)d_in[5];
  const float* w_lat  = (const float*)d_in[6];
  const float* b_lat  = (const float*)d_in[7];
  const float* w_sm   = (const float*)d_in[8];
  const float* b_sm   = (const float*)d_in[9];
  const float* q_embed= (const float*)d_in[10];
  const float* q_pos  = (const float*)d_in[11];
  const float* Wq     = (const float*)d_in[12];
  const float* bq     = (const float*)d_in[13];
  const float* Wo     = (const float*)d_in[14];
  const float* bo     = (const float*)d_in[15];
  const float* Wp1    = (const float*)d_in[16];
  const float* bp1    = (const float*)d_in[17];
  const float* Wp2    = (const float*)d_in[18];
  const float* bp2    = (const float*)d_in[19];
  const float* w_r1   = (const float*)d_in[20];
  const float* b_r1   = (const float*)d_in[21];
  const float* w_r2   = (const float*)d_in[22];
  const float* b_r2   = (const float*)d_in[23];
  const float* w_b1   = (const float*)d_in[24];
  const float* b_b1   = (const float*)d_in[25];
  const float* w_b2   = (const float*)d_in[26];
  const float* b_b2   = (const float*)d_in[27];
  const float* w_cls  = (const float*)d_in[28];
  const float* b_cls  = (const float*)d_in[29];
  float* out = (float*)d_out;

  float* ws = (float*)d_ws;
  size_t off = 0;
  auto alloc = [&](size_t n) { float* p = ws + off; off += n; return p; };
  float* tmean   = alloc((size_t)BB * CIN * HW);        // 4 MB
  float* x       = alloc((size_t)BB * DM * HW);         // 8 MB
  float* x2      = alloc((size_t)BB * DM * HW);         // 8 MB
  float* fcl     = alloc((size_t)BB * HW * DM);         // 8 MB (channel-last)
  float* queries = alloc((size_t)BB * NQ * DM);
  float* boxes   = alloc((size_t)BB * NQ * 4);
  float* h1      = alloc((size_t)BB * NQ * DM);
  float* ref     = alloc((size_t)BB * NQ * 2 * NP);
  float* flat    = alloc((size_t)BB * NQ * NP * PS * PS * DM); // 44 MB
  float* pv1     = alloc((size_t)BB * NQ * NP * DM);
  float* pvm     = alloc((size_t)BB * NQ * DM);
  float* kv      = alloc((size_t)BB * NQ * DM);
  float* qbuf    = alloc((size_t)BB * NQ * DM);
  float* ao      = alloc((size_t)BB * NQ * DM);
  float* hb      = alloc((size_t)BB * NQ * DM);
  (void)ws_size; (void)in_sizes; (void)n_in; (void)out_size;

  k_tmean<<<2048, 256, 0, stream>>>(feat, w_tf, b_tf, tmean);
  k_proj<<<2048, 256, 0, stream>>>(tmean, w_in, b_in, x);
  k_lat<<<2048, 256, 0, stream>>>(x, w_lat, b_lat, x2);
  k_smooth<<<2048, 256, 0, stream>>>(x2, w_sm, b_sm, fcl);
  k_init<<<600, 256, 0, stream>>>(q_embed, q_pos, pb, queries, boxes);

  const int M6 = BB * NQ;                 // 600
  const int Mp = BB * NQ * NP;            // 4800
  const int Kp = PS * PS * DM;            // 2304
  dim3 g600((M6 + 63) / 64, DM / 64);     // (10,4)
  dim3 g4800((Mp + 63) / 64, DM / 64);    // (75,4)

  for (int l = 0; l < NL; ++l) {
    k_gemm<1, false><<<g600, 256, 0, stream>>>(queries, w_r1, b_r1, nullptr, h1, M6, DM, DM);
    k_r2ref<<<(M6 * 16 + 255) / 256, 256, 0, stream>>>(h1, w_r2, b_r2, boxes, ref);
    k_sample<<<Mp, 256, 0, stream>>>(fcl, ref, flat);
    k_gemm<1, false><<<g4800, 256, 0, stream>>>(flat, Wp1 + (size_t)l * DM * Kp,
                                                bp1 + (size_t)l * DM, nullptr, pv1, Mp, DM, Kp);
    k_pmean<<<(M6 * DM + 255) / 256, 256, 0, stream>>>(pv1, pvm);
    k_gemm<0, false><<<g600, 256, 0, stream>>>(pvm, Wp2 + (size_t)l * DM * DM,
                                               bp2 + (size_t)l * DM, nullptr, kv, M6, DM, DM);
    k_gemm<0, false><<<g600, 256, 0, stream>>>(queries, Wq + (size_t)l * DM * DM,
                                               bq + (size_t)l * DM, nullptr, qbuf, M6, DM, DM);
    k_attn<<<M6, 256, 0, stream>>>(qbuf, kv, ao);
    k_gemm<0, true><<<g600, 256, 0, stream>>>(ao, Wo + (size_t)l * DM * DM,
                                              bo + (size_t)l * DM, queries, queries, M6, DM, DM);
    k_gemm<1, false><<<g600, 256, 0, stream>>>(queries, w_b1, b_b1, nullptr, hb, M6, DM, DM);
    k_box<<<(M6 * 4 + 255) / 256, 256, 0, stream>>>(hb, w_b2, b_b2, boxes);
  }
  k_final<<<(BB * NQ * 4 + 255) / 256, 256, 0, stream>>>(queries, w_cls, b_cls, boxes, out);
}

// Round 2
// 1536.147 us; speedup vs baseline: 1.7769x; 1.7769x over previous
//
#include <hip/hip_runtime.h>
#include <hip/hip_bf16.h>
#include <math.h>

// Problem constants
#define BB 2
#define TT 4
#define CIN 128
#define DM 256
#define NQ 300
#define NP 8
#define PS 3
#define NL 6
#define HW 4096   // 64*64
#define KP 2304   // 3*3*256

typedef __attribute__((ext_vector_type(8))) short short8;
typedef __attribute__((ext_vector_type(4))) float f32x4;
typedef unsigned short ushort_t;

static __device__ __forceinline__ ushort_t f2bf(float f) {
  __hip_bfloat16 h = __float2bfloat16(f);
  return *reinterpret_cast<ushort_t*>(&h);
}

// ---------------------------------------------------------------------------
// K1: temporal conv (k=3, pad 1 on T) + mean over T, fused via per-u coeffs.
__global__ __launch_bounds__(256) void k_tmean(const float* __restrict__ feat,
                                               const float* __restrict__ w_tf,
                                               const float* __restrict__ b_tf,
                                               float* __restrict__ tmean) {
  int bi = blockIdx.x;
  int tileS = bi & 15;
  int cg = (bi >> 4) & 63;
  int b = bi >> 10;
  int c0 = cg * 2;
  int s = tileS * 256 + threadIdx.x;
  float acc0 = 0.f, acc1 = 0.f;
  const float* fb = feat + (size_t)b * TT * CIN * HW;
  for (int ci = 0; ci < CIN; ++ci) {
    float f0 = fb[(0 * CIN + ci) * HW + s];
    float f1 = fb[(1 * CIN + ci) * HW + s];
    float f2 = fb[(2 * CIN + ci) * HW + s];
    float f3 = fb[(3 * CIN + ci) * HW + s];
    float f12 = f1 + f2;
    {
      const float* wp = w_tf + ((size_t)(c0 + 0) * CIN + ci) * 3;
      float w0 = wp[0], w1 = wp[1], w2 = wp[2];
      acc0 += f0 * (w0 + w1) + f12 * (w0 + w1 + w2) + f3 * (w1 + w2);
    }
    {
      const float* wp = w_tf + ((size_t)(c0 + 1) * CIN + ci) * 3;
      float w0 = wp[0], w1 = wp[1], w2 = wp[2];
      acc1 += f0 * (w0 + w1) + f12 * (w0 + w1 + w2) + f3 * (w1 + w2);
    }
  }
  tmean[((size_t)b * CIN + c0 + 0) * HW + s] = acc0 * 0.25f + b_tf[c0 + 0];
  tmean[((size_t)b * CIN + c0 + 1) * HW + s] = acc1 * 0.25f + b_tf[c0 + 1];
}

// ---------------------------------------------------------------------------
// K2: input projection (128->256, 1x1) + bias + sine positional encoding.
__global__ __launch_bounds__(256) void k_proj(const float* __restrict__ tmean,
                                              const float* __restrict__ w_in,
                                              const float* __restrict__ b_in,
                                              float* __restrict__ x) {
  int bi = blockIdx.x;
  int tileS = bi & 15;
  int dg = (bi >> 4) & 63;
  int b = bi >> 10;
  int d0 = dg * 4;
  int s = tileS * 256 + threadIdx.x;
  float acc[4] = {0.f, 0.f, 0.f, 0.f};
  const float* tb = tmean + (size_t)b * CIN * HW;
  for (int c = 0; c < CIN; ++c) {
    float t = tb[c * HW + s];
    acc[0] += t * w_in[(d0 + 0) * CIN + c];
    acc[1] += t * w_in[(d0 + 1) * CIN + c];
    acc[2] += t * w_in[(d0 + 2) * CIN + c];
    acc[3] += t * w_in[(d0 + 3) * CIN + c];
  }
  int h = s >> 6, w = s & 63;
  const float TWO_PI = 6.28318530717958647692f;
  float yn = (float)(h + 1) / (64.0f + 1e-6f) * TWO_PI;
  float xn = (float)(w + 1) / (64.0f + 1e-6f) * TWO_PI;
#pragma unroll
  for (int j = 0; j < 4; ++j) {
    int d = d0 + j;
    int dd = (d < 128) ? d : (d - 128);
    int ii = dd >> 1;
    float e = (2.0f * (float)(ii >> 1)) / 64.0f;
    float dimt = powf(10000.0f, e);
    float ang = ((d < 128) ? yn : xn) / dimt;
    float pos = (dd & 1) ? cosf(ang) : sinf(ang);
    x[((size_t)b * DM + d) * HW + s] = acc[j] + b_in[d] + pos;
  }
}

// ---------------------------------------------------------------------------
// transpose x (B,256,HW) fp32 -> xcl (B*HW,256) bf16. grid (32,4)
__global__ __launch_bounds__(256) void k_xpose(const float* __restrict__ x,
                                               ushort_t* __restrict__ xcl) {
  int s = blockIdx.x * 256 + threadIdx.x;   // global pixel
  int b = s >> 12, sp = s & 4095;
  int c0 = blockIdx.y * 64;
  const float* xb = x + (size_t)b * DM * HW + sp;
  for (int cc = 0; cc < 64; cc += 8) {
    short8 v;
#pragma unroll
    for (int j = 0; j < 8; ++j)
      v[j] = (short)f2bf(xb[(size_t)(c0 + cc + j) * HW]);
    *(short8*)(xcl + (size_t)s * DM + c0 + cc) = v;
  }
}

// ---------------------------------------------------------------------------
// zero a buffer (uint4 granularity)
__global__ void k_zero(uint4* __restrict__ p, int n) {
  int i = blockIdx.x * 256 + threadIdx.x;
  if (i < n) p[i] = make_uint4(0u, 0u, 0u, 0u);
}

// ---------------------------------------------------------------------------
// weight converts
__global__ void k_cvt_plain(const float* __restrict__ src, ushort_t* __restrict__ dst, int n4) {
  int i = blockIdx.x * 256 + threadIdx.x;
  if (i >= n4) return;
  float4 v = ((const float4*)src)[i];
  dst[i * 4 + 0] = f2bf(v.x);
  dst[i * 4 + 1] = f2bf(v.y);
  dst[i * 4 + 2] = f2bf(v.z);
  dst[i * 4 + 3] = f2bf(v.w);
}

// wsm_r[n*2304 + t*256 + c] = w_sm[(n*256+c)*9 + t]   (scale-0 weights only)
__global__ void k_cvt_wsm(const float* __restrict__ wsm, ushort_t* __restrict__ dst) {
  int i = blockIdx.x * 256 + threadIdx.x;   // < 256*2304
  int n = i / KP;
  int r = i - n * KP;
  int t = r >> 8, c = r & 255;
  dst[i] = f2bf(wsm[((size_t)(n * 256 + c)) * 9 + t]);
}

// ---------------------------------------------------------------------------
// bf16 MFMA GEMM: C[m,n] = act( sum_k A[m,k]*W[n,k] + bias[n] )
// A (M,K) bf16 row-major, W (N,K) bf16 row-major. M%64==0, N%64==0, K%32==0.
// BM=BN=64, BK=32, 256 threads (4 waves, each 32x32).
// PADOUT=1: write bf16 into padded (B,66,66,256) buffer instead of fp32 C.
template <int ACT, int PADOUT>
__global__ __launch_bounds__(256) void k_gemm_bf16(const ushort_t* __restrict__ A,
                                                   const ushort_t* __restrict__ W,
                                                   const float* __restrict__ bias,
                                                   float* __restrict__ Cf,
                                                   ushort_t* __restrict__ Cb,
                                                   int M, int N, int K) {
  __shared__ ushort_t As[64 * 40];
  __shared__ ushort_t Bs[64 * 40];
  int tid = threadIdx.x;
  int bm = blockIdx.x * 64, bn = blockIdx.y * 64;
  int w = tid >> 6, lane = tid & 63;
  int wm = (w & 1) * 32, wn = (w >> 1) * 32;
  int q = lane >> 4, ml = lane & 15;
  f32x4 acc[2][2] = {};
  int srow = tid >> 2, scol = (tid & 3) * 8;
  const ushort_t* Ag = A + (size_t)(bm + srow) * K + scol;
  const ushort_t* Wg = W + (size_t)(bn + srow) * K + scol;
  for (int k0 = 0; k0 < K; k0 += 32) {
    short8 av = *(const short8*)(Ag + k0);
    short8 wv = *(const short8*)(Wg + k0);
    *(short8*)(As + srow * 40 + scol) = av;
    *(short8*)(Bs + srow * 40 + scol) = wv;
    __syncthreads();
    short8 a0 = *(const short8*)(As + (wm + ml) * 40 + q * 8);
    short8 a1 = *(const short8*)(As + (wm + 16 + ml) * 40 + q * 8);
    short8 b0 = *(const short8*)(Bs + (wn + ml) * 40 + q * 8);
    short8 b1 = *(const short8*)(Bs + (wn + 16 + ml) * 40 + q * 8);
    acc[0][0] = __builtin_amdgcn_mfma_f32_16x16x32_bf16(a0, b0, acc[0][0], 0, 0, 0);
    acc[0][1] = __builtin_amdgcn_mfma_f32_16x16x32_bf16(a0, b1, acc[0][1], 0, 0, 0);
    acc[1][0] = __builtin_amdgcn_mfma_f32_16x16x32_bf16(a1, b0, acc[1][0], 0, 0, 0);
    acc[1][1] = __builtin_amdgcn_mfma_f32_16x16x32_bf16(a1, b1, acc[1][1], 0, 0, 0);
    __syncthreads();
  }
#pragma unroll
  for (int i = 0; i < 2; ++i) {
#pragma unroll
    for (int j = 0; j < 2; ++j) {
      int cn = bn + wn + j * 16 + ml;
      float bsv = bias ? bias[cn] : 0.f;
#pragma unroll
      for (int r = 0; r < 4; ++r) {
        int rm = bm + wm + i * 16 + q * 4 + r;
        float v = acc[i][j][r] + bsv;
        if (ACT == 1) v = fmaxf(v, 0.f);
        if (PADOUT) {
          int b = rm >> 12, rem = rm & 4095;
          int y = rem >> 6, xx = rem & 63;
          Cb[(((size_t)(b * 66 + y + 1)) * 66 + xx + 1) * 256 + cn] = f2bf(v);
        } else {
          Cf[(size_t)rm * N + cn] = v;
        }
      }
    }
  }
}

// ---------------------------------------------------------------------------
// im2col: x2p (B,66,66,256) bf16 -> Acol (B*HW, 2304) bf16. grid = B*HW
__global__ __launch_bounds__(256) void k_im2col(const ushort_t* __restrict__ x2p,
                                                ushort_t* __restrict__ Acol) {
  int row = blockIdx.x;
  int b = row >> 12, rem = row & 4095;
  int y = rem >> 6, x = rem & 63;
  int c = threadIdx.x;
  ushort_t* op = Acol + (size_t)row * KP + c;
#pragma unroll
  for (int ky = 0; ky < 3; ++ky)
#pragma unroll
    for (int kx = 0; kx < 3; ++kx) {
      ushort_t v = x2p[(((size_t)(b * 66 + y + ky)) * 66 + x + kx) * 256 + c];
      op[(ky * 3 + kx) * 256] = v;
    }
}

// ---------------------------------------------------------------------------
__global__ void k_init(const float* __restrict__ qe, const float* __restrict__ qp,
                       const float* __restrict__ pb, float* __restrict__ queries,
                       float* __restrict__ boxes) {
  int i = blockIdx.x * 256 + threadIdx.x;
  if (i < BB * NQ * DM) {
    int rd = i % (NQ * DM);
    queries[i] = qe[rd] + qp[rd];
  }
  if (i < BB * NQ * 4) boxes[i] = pb[i];
}

// ---------------------------------------------------------------------------
// fp32 GEMM for the small per-layer mats (M=600, N=256, K=256).
template <int ACT, bool RES>
__global__ __launch_bounds__(256) void k_gemm(const float* __restrict__ A,
                                              const float* __restrict__ W,
                                              const float* __restrict__ bias,
                                              const float* __restrict__ res,
                                              float* __restrict__ C,
                                              int M, int N, int K) {
  __shared__ float As[16][64];
  __shared__ float Bs[16][64];
  int tid = threadIdx.x;
  int bm = blockIdx.x * 64;
  int bn = blockIdx.y * 64;
  int tx = tid & 15, ty = tid >> 4;
  int lr = tid >> 2;
  int lc = (tid & 3) << 2;
  float acc[4][4] = {};
  for (int k0 = 0; k0 < K; k0 += 16) {
    int gm = bm + lr;
    float4 av = make_float4(0.f, 0.f, 0.f, 0.f);
    if (gm < M) av = *(const float4*)(A + (size_t)gm * K + k0 + lc);
    As[lc + 0][lr] = av.x; As[lc + 1][lr] = av.y;
    As[lc + 2][lr] = av.z; As[lc + 3][lr] = av.w;
    int gn = bn + lr;
    float4 bv = make_float4(0.f, 0.f, 0.f, 0.f);
    if (gn < N) bv = *(const float4*)(W + (size_t)gn * K + k0 + lc);
    Bs[lc + 0][lr] = bv.x; Bs[lc + 1][lr] = bv.y;
    Bs[lc + 2][lr] = bv.z; Bs[lc + 3][lr] = bv.w;
    __syncthreads();
#pragma unroll
    for (int kk = 0; kk < 16; ++kk) {
      float4 a4 = *(const float4*)&As[kk][ty * 4];
      float4 b4 = *(const float4*)&Bs[kk][tx * 4];
      float a[4] = {a4.x, a4.y, a4.z, a4.w};
      float bb4[4] = {b4.x, b4.y, b4.z, b4.w};
#pragma unroll
      for (int i = 0; i < 4; ++i)
#pragma unroll
        for (int j = 0; j < 4; ++j) acc[i][j] += a[i] * bb4[j];
    }
    __syncthreads();
  }
#pragma unroll
  for (int i = 0; i < 4; ++i) {
    int m = bm + ty * 4 + i;
    if (m >= M) continue;
#pragma unroll
    for (int j = 0; j < 4; ++j) {
      int n = bn + tx * 4 + j;
      if (n >= N) continue;
      float v = acc[i][j];
      if (bias) v += bias[n];
      if (ACT == 1) v = fmaxf(v, 0.f);
      if (RES) v += res[(size_t)m * N + n];
      C[(size_t)m * N + n] = v;
    }
  }
}

// ---------------------------------------------------------------------------
__global__ void k_r2ref(const float* __restrict__ h1, const float* __restrict__ w_r2,
                        const float* __restrict__ b_r2, const float* __restrict__ boxes,
                        float* __restrict__ ref) {
  int i = blockIdx.x * 256 + threadIdx.x;
  if (i >= BB * NQ * 2 * NP) return;
  int row = i >> 4, o = i & 15;
  const float* hp = h1 + (size_t)row * DM;
  const float* wp = w_r2 + (size_t)o * DM;
  float acc = b_r2[o];
  for (int k = 0; k < DM; ++k) acc += hp[k] * wp[k];
  float ro = 0.5f * tanhf(acc);
  int ax = o & 1;
  float v = boxes[row * 4 + ax] + ro;
  ref[i] = fminf(fmaxf(v, 0.f), 1.f);
}

// ---------------------------------------------------------------------------
// Bilinear patch sampling from channel-last fcl (fp32), writes bf16 flat.
__global__ __launch_bounds__(256) void k_sample(const float* __restrict__ fcl,
                                                const float* __restrict__ ref,
                                                ushort_t* __restrict__ flat) {
  int blk = blockIdx.x;             // (b*NQ+q)*NP + p
  int c = threadIdx.x;
  int row = blk >> 3;
  int b = row / NQ;
  float rx = ref[blk * 2 + 0];
  float ry = ref[blk * 2 + 1];
  const float* fb = fcl + (size_t)b * HW * DM;
  ushort_t* op = flat + (size_t)blk * KP;
#pragma unroll
  for (int jy = 0; jy < 3; ++jy) {
    float yy = (ry + (float)(jy - 1) * (1.0f / 64.0f)) * 63.0f;
    yy = fminf(fmaxf(yy, 0.f), 63.0f);
    float y0f = floorf(yy);
    float wy = yy - y0f;
    int y0 = (int)y0f;
    int y1 = min(y0 + 1, 63);
#pragma unroll
    for (int jx = 0; jx < 3; ++jx) {
      float xx = (rx + (float)(jx - 1) * (1.0f / 64.0f)) * 63.0f;
      xx = fminf(fmaxf(xx, 0.f), 63.0f);
      float x0f = floorf(xx);
      float wx = xx - x0f;
      int x0 = (int)x0f;
      int x1 = min(x0 + 1, 63);
      float v00 = fb[(y0 * 64 + x0) * DM + c];
      float v01 = fb[(y0 * 64 + x1) * DM + c];
      float v10 = fb[(y1 * 64 + x0) * DM + c];
      float v11 = fb[(y1 * 64 + x1) * DM + c];
      float v = v00 * (1.f - wx) * (1.f - wy) + v01 * wx * (1.f - wy) +
                v10 * (1.f - wx) * wy + v11 * wx * wy;
      op[(jy * 3 + jx) * DM + c] = f2bf(v);
    }
  }
}

// ---------------------------------------------------------------------------
__global__ void k_pmean(const float* __restrict__ pv1, float* __restrict__ pvm) {
  int i = blockIdx.x * 256 + threadIdx.x;
  if (i >= BB * NQ * DM) return;
  int row = i >> 8, d = i & 255;
  float s = 0.f;
#pragma unroll
  for (int p = 0; p < NP; ++p) s += pv1[((size_t)row * NP + p) * DM + d];
  pvm[i] = s * 0.125f;
}

// ---------------------------------------------------------------------------
__global__ __launch_bounds__(256) void k_attn(const float* __restrict__ qb,
                                              const float* __restrict__ kv,
                                              float* __restrict__ ao) {
  __shared__ float sc[512];
  __shared__ float qs[256];
  __shared__ float red[256];
  int row = blockIdx.x;
  int b = row / NQ;
  int tid = threadIdx.x;
  qs[tid] = qb[(size_t)row * DM + tid];
  __syncthreads();
  const float* kvb = kv + (size_t)b * NQ * DM;
  for (int k = tid; k < 512; k += 256) {
    float v = -1e30f;
    if (k < NQ) {
      const float* kp = kvb + (size_t)k * DM;
      float a = 0.f;
      for (int d = 0; d < DM; ++d) a += qs[d] * kp[d];
      v = a * (1.0f / 16.0f);
    }
    sc[k] = v;
  }
  __syncthreads();
  red[tid] = fmaxf(sc[tid], sc[tid + 256]);
  __syncthreads();
  for (int st = 128; st > 0; st >>= 1) {
    if (tid < st) red[tid] = fmaxf(red[tid], red[tid + st]);
    __syncthreads();
  }
  float mx = red[0];
  __syncthreads();
  float e0 = (tid < NQ) ? expf(sc[tid] - mx) : 0.f;
  float e1 = (tid + 256 < NQ) ? expf(sc[tid + 256] - mx) : 0.f;
  sc[tid] = e0;
  sc[tid + 256] = e1;
  red[tid] = e0 + e1;
  __syncthreads();
  for (int st = 128; st > 0; st >>= 1) {
    if (tid < st) red[tid] += red[tid + st];
    __syncthreads();
  }
  float inv = 1.0f / red[0];
  __syncthreads();
  float acc = 0.f;
  for (int k = 0; k < NQ; ++k) acc += sc[k] * kvb[(size_t)k * DM + tid];
  ao[(size_t)row * DM + tid] = acc * inv;
}

// ---------------------------------------------------------------------------
__global__ void k_box(const float* __restrict__ hb, const float* __restrict__ w_b2,
                      const float* __restrict__ b_b2, float* __restrict__ boxes) {
  int i = blockIdx.x * 256 + threadIdx.x;
  if (i >= BB * NQ * 4) return;
  int row = i >> 2, j = i & 3;
  const float* hp = hb + (size_t)row * DM;
  const float* wp = w_b2 + (size_t)j * DM;
  float a = b_b2[j];
  for (int k = 0; k < DM; ++k) a += hp[k] * wp[k];
  float delta = 1.0f / (1.0f + expf(-a));
  float v = boxes[i] + 0.1f * tanhf(delta - 0.5f);
  boxes[i] = fminf(fmaxf(v, 0.f), 1.f);
}

// ---------------------------------------------------------------------------
__global__ void k_final(const float* __restrict__ queries, const float* __restrict__ w_cls,
                        const float* __restrict__ b_cls, const float* __restrict__ boxes,
                        float* __restrict__ out) {
  int i = blockIdx.x * 256 + threadIdx.x;
  if (i < BB * NQ) {
    const float* qp = queries + (size_t)i * DM;
    float a = b_cls[0];
    for (int k = 0; k < DM; ++k) a += qp[k] * w_cls[k];
    out[i] = a;
  }
  if (i < BB * NQ * 4) out[BB * NQ + i] = boxes[i];
}

// ---------------------------------------------------------------------------
extern "C" void kernel_launch(void* const* d_in, const int* in_sizes, int n_in,
                              void* d_out, int out_size, void* d_ws, size_t ws_size,
                              hipStream_t stream) {
  const float* feat   = (const float*)d_in[0];
  const float* pb     = (const float*)d_in[1];
  const float* w_tf   = (const float*)d_in[2];
  const float* b_tf   = (const float*)d_in[3];
  const float* w_in   = (const float*)d_in[4];
  const float* b_in   = (const float*)d_in[5];
  const float* w_lat  = (const float*)d_in[6];
  const float* b_lat  = (const float*)d_in[7];
  const float* w_sm   = (const float*)d_in[8];
  const float* b_sm   = (const float*)d_in[9];
  const float* q_embed= (const float*)d_in[10];
  const float* q_pos  = (const float*)d_in[11];
  const float* Wq     = (const float*)d_in[12];
  const float* bq     = (const float*)d_in[13];
  const float* Wo     = (const float*)d_in[14];
  const float* bo     = (const float*)d_in[15];
  const float* Wp1    = (const float*)d_in[16];
  const float* bp1    = (const float*)d_in[17];
  const float* Wp2    = (const float*)d_in[18];
  const float* bp2    = (const float*)d_in[19];
  const float* w_r1   = (const float*)d_in[20];
  const float* b_r1   = (const float*)d_in[21];
  const float* w_r2   = (const float*)d_in[22];
  const float* b_r2   = (const float*)d_in[23];
  const float* w_b1   = (const float*)d_in[24];
  const float* b_b1   = (const float*)d_in[25];
  const float* w_b2   = (const float*)d_in[26];
  const float* b_b2   = (const float*)d_in[27];
  const float* w_cls  = (const float*)d_in[28];
  const float* b_cls  = (const float*)d_in[29];
  float* out = (float*)d_out;

  float* ws = (float*)d_ws;
  size_t off = 0;
  auto alloc = [&](size_t n) { float* p = ws + off; off += n; return p; };
  // big shared region: Acol (18.9M ushort) / xcl (2.1M ushort) / flat (11.1M ushort)
  float* big    = alloc(9437184);
  float* tmean  = alloc(1048576);   // later: h1,pvm,kv,qbuf,ao,hb (6 x 153600)
  float* xbuf   = alloc(2097152);   // later: pv1 (1228800)
  float* x2pf   = alloc(1115136);   // bf16 (B,66,66,256)
  float* fcl    = alloc(2097152);
  float* wlatf  = alloc(32768);     // bf16 256x256
  float* wsmf   = alloc(294912);    // bf16 256x2304
  float* wp1f   = alloc(1769472);   // bf16 6x256x2304
  float* queries= alloc(153600);
  float* boxes  = alloc(2400);
  float* ref    = alloc(9600);
  (void)ws_size; (void)in_sizes; (void)n_in; (void)out_size;

  ushort_t* Acol = (ushort_t*)big;
  ushort_t* xcl  = (ushort_t*)big;
  ushort_t* flat = (ushort_t*)big;
  ushort_t* x2p  = (ushort_t*)x2pf;
  ushort_t* wlat_bf = (ushort_t*)wlatf;
  ushort_t* wsm_bf  = (ushort_t*)wsmf;
  ushort_t* wp1_bf  = (ushort_t*)wp1f;
  float* h1   = tmean;
  float* pvm  = tmean + 153600;
  float* kv   = tmean + 307200;
  float* qbuf = tmean + 460800;
  float* ao   = tmean + 614400;
  float* hb   = tmean + 768000;
  float* pv1  = xbuf;

  // --- weight converts + pad-zero (independent) ---
  k_cvt_plain<<<(65536 / 4 + 255) / 256, 256, 0, stream>>>(w_lat, wlat_bf, 65536 / 4);
  k_cvt_wsm<<<(256 * KP + 255) / 256, 256, 0, stream>>>(w_sm, wsm_bf);
  k_cvt_plain<<<(NL * 256 * KP / 4 + 255) / 256, 256, 0, stream>>>(Wp1, wp1_bf, NL * 256 * KP / 4);
  k_zero<<<(278784 + 255) / 256, 256, 0, stream>>>((uint4*)x2p, 278784);

  // --- backbone ---
  k_tmean<<<2048, 256, 0, stream>>>(feat, w_tf, b_tf, tmean);
  k_proj<<<2048, 256, 0, stream>>>(tmean, w_in, b_in, xbuf);
  k_xpose<<<dim3(32, 4), 256, 0, stream>>>(xbuf, xcl);
  // lateral 1x1 -> padded bf16 channel-last
  k_gemm_bf16<0, 1><<<dim3(128, 4), 256, 0, stream>>>(xcl, wlat_bf, b_lat, nullptr, x2p,
                                                      BB * HW, 256, 256);
  k_im2col<<<BB * HW, 256, 0, stream>>>(x2p, Acol);
  // 3x3 smooth conv as GEMM -> fcl fp32 channel-last
  k_gemm_bf16<0, 0><<<dim3(128, 4), 256, 0, stream>>>(Acol, wsm_bf, b_sm, fcl, nullptr,
                                                      BB * HW, 256, KP);
  k_init<<<600, 256, 0, stream>>>(q_embed, q_pos, pb, queries, boxes);

  const int M6 = BB * NQ;                 // 600
  const int Mp = BB * NQ * NP;            // 4800
  dim3 g600((M6 + 63) / 64, DM / 64);     // (10,4)
  dim3 gp(Mp / 64, DM / 64);              // (75,4)

  for (int l = 0; l < NL; ++l) {
    k_gemm<1, false><<<g600, 256, 0, stream>>>(queries, w_r1, b_r1, nullptr, h1, M6, DM, DM);
    k_r2ref<<<(M6 * 16 + 255) / 256, 256, 0, stream>>>(h1, w_r2, b_r2, boxes, ref);
    k_sample<<<Mp, 256, 0, stream>>>(fcl, ref, flat);
    k_gemm_bf16<1, 0><<<gp, 256, 0, stream>>>(flat, wp1_bf + (size_t)l * 256 * KP,
                                              bp1 + (size_t)l * DM, pv1, nullptr, Mp, DM, KP);
    k_pmean<<<(M6 * DM + 255) / 256, 256, 0, stream>>>(pv1, pvm);
    k_gemm<0, false><<<g600, 256, 0, stream>>>(pvm, Wp2 + (size_t)l * DM * DM,
                                               bp2 + (size_t)l * DM, nullptr, kv, M6, DM, DM);
    k_gemm<0, false><<<g600, 256, 0, stream>>>(queries, Wq + (size_t)l * DM * DM,
                                               bq + (size_t)l * DM, nullptr, qbuf, M6, DM, DM);
    k_attn<<<M6, 256, 0, stream>>>(qbuf, kv, ao);
    k_gemm<0, true><<<g600, 256, 0, stream>>>(ao, Wo + (size_t)l * DM * DM,
                                              bo + (size_t)l * DM, queries, queries, M6, DM, DM);
    k_gemm<1, false><<<g600, 256, 0, stream>>>(queries, w_b1, b_b1, nullptr, hb, M6, DM, DM);
    k_box<<<(M6 * 4 + 255) / 256, 256, 0, stream>>>(hb, w_b2, b_b2, boxes);
  }
  k_final<<<(BB * NQ * 4 + 255) / 256, 256, 0, stream>>>(queries, w_cls, b_cls, boxes, out);
}

// Round 4
// 1057.131 us; speedup vs baseline: 2.5821x; 1.4531x over previous
//
#include <hip/hip_runtime.h>
#include <hip/hip_bf16.h>
#include <math.h>

// Problem constants
#define BB 2
#define TT 4
#define CIN 128
#define DM 256
#define NQ 300
#define NP 8
#define PS 3
#define NL 6
#define HW 4096   // 64*64
#define KP 2304   // 3*3*256

typedef __attribute__((ext_vector_type(8))) short short8;
typedef __attribute__((ext_vector_type(4))) float f32x4;
typedef unsigned short ushort_t;

static __device__ __forceinline__ ushort_t f2bf(float f) {
  __hip_bfloat16 h = __float2bfloat16(f);
  return *reinterpret_cast<ushort_t*>(&h);
}
static __device__ __forceinline__ float bf2f(ushort_t u) {
  return __uint_as_float(((unsigned)u) << 16);
}

// ---------------------------------------------------------------------------
// Compose temporal-conv + input-projection weights:
// Wcomb[d][u*128+ci] = 0.25 * sum_c w_in[d,c] * tc(c,ci,u)
// tc: u=0 -> w0+w1 ; u=1,2 -> w0+w1+w2 ; u=3 -> w1+w2  (w* = w_tf[c,ci,*])
// bias_comb[d] = b_in[d] + sum_c w_in[d,c]*b_tf[c]
__global__ __launch_bounds__(512) void k_wcomb(const float* __restrict__ w_tf,
                                               const float* __restrict__ b_tf,
                                               const float* __restrict__ w_in,
                                               const float* __restrict__ b_in,
                                               ushort_t* __restrict__ wcomb,
                                               float* __restrict__ bias_comb) {
  int d = blockIdx.x;
  int k = threadIdx.x;
  int u = k >> 7, ci = k & 127;
  float acc = 0.f;
  for (int c = 0; c < 128; ++c) {
    const float* wp = w_tf + ((size_t)(c * 128 + ci)) * 3;
    float w0 = wp[0], w1 = wp[1], w2 = wp[2];
    float coef = (u == 0) ? (w0 + w1) : (u == 3) ? (w1 + w2) : (w0 + w1 + w2);
    acc += w_in[d * 128 + c] * coef;
  }
  wcomb[(size_t)d * 512 + k] = f2bf(0.25f * acc);
  if (k == 0) {
    float a = b_in[d];
    for (int c = 0; c < 128; ++c) a += w_in[d * 128 + c] * b_tf[c];
    bias_comb[d] = a;
  }
}

// ---------------------------------------------------------------------------
// Fused backbone GEMM: xcl[b*HW+s][d] = bf16( feat_t[s][:] . Wcomb[d][:] +
//                                             bias_comb[d] + pos(d, y, x) )
__global__ __launch_bounds__(256) void k_feat(const float* __restrict__ feat,
                                              const ushort_t* __restrict__ wcomb,
                                              const float* __restrict__ bias_comb,
                                              ushort_t* __restrict__ xcl) {
  __shared__ ushort_t As[64 * 40];
  __shared__ ushort_t Bs[64 * 40];
  __shared__ float dimt_s[256];
  int tid = threadIdx.x;
  {
    int dd = tid & 127;
    int ii = dd >> 1;
    float e = (2.0f * (float)(ii >> 1)) / 64.0f;
    dimt_s[tid] = powf(10000.0f, e);
  }
  int bm = blockIdx.x * 64, bn = blockIdx.y * 64;
  int b = bm >> 12;
  int s0 = bm & 4095;
  int w = tid >> 6, lane = tid & 63;
  int wm = (w & 1) * 32, wn = (w >> 1) * 32;
  int q = lane >> 4, ml = lane & 15;
  int srow = tid >> 2, scol = (tid & 3) * 8;
  const ushort_t* Wg = wcomb + (size_t)(bn + srow) * 512 + scol;
  f32x4 acc[2][2] = {};
  for (int k0 = 0; k0 < 512; k0 += 32) {
    short8 wv = *(const short8*)(Wg + k0);
#pragma unroll
    for (int j = 0; j < 8; ++j) {
      int kk = w * 8 + j;
      int k = k0 + kk;
      int u = k >> 7, ci = k & 127;
      float v = feat[(((size_t)(b * 4 + u) * 128 + ci) << 12) + s0 + lane];
      As[lane * 40 + kk] = f2bf(v);
    }
    *(short8*)(Bs + srow * 40 + scol) = wv;
    __syncthreads();
    short8 a0 = *(const short8*)(As + (wm + ml) * 40 + q * 8);
    short8 a1 = *(const short8*)(As + (wm + 16 + ml) * 40 + q * 8);
    short8 b0 = *(const short8*)(Bs + (wn + ml) * 40 + q * 8);
    short8 b1 = *(const short8*)(Bs + (wn + 16 + ml) * 40 + q * 8);
    acc[0][0] = __builtin_amdgcn_mfma_f32_16x16x32_bf16(a0, b0, acc[0][0], 0, 0, 0);
    acc[0][1] = __builtin_amdgcn_mfma_f32_16x16x32_bf16(a0, b1, acc[0][1], 0, 0, 0);
    acc[1][0] = __builtin_amdgcn_mfma_f32_16x16x32_bf16(a1, b0, acc[1][0], 0, 0, 0);
    acc[1][1] = __builtin_amdgcn_mfma_f32_16x16x32_bf16(a1, b1, acc[1][1], 0, 0, 0);
    __syncthreads();
  }
  const float FKT = 6.28318530717958647692f / 64.000001f;
#pragma unroll
  for (int i2 = 0; i2 < 2; ++i2) {
#pragma unroll
    for (int j2 = 0; j2 < 2; ++j2) {
      int cn = bn + wn + j2 * 16 + ml;
      float dimt = dimt_s[cn];
      float bC = bias_comb[cn];
      bool isx = cn >= 128;
      bool isc = cn & 1;
#pragma unroll
      for (int r = 0; r < 4; ++r) {
        int rm = bm + wm + i2 * 16 + q * 4 + r;
        int s = rm & 4095;
        int y = s >> 6, x = s & 63;
        float ang = (float)((isx ? x : y) + 1) * FKT / dimt;
        float pos = isc ? cosf(ang) : sinf(ang);
        xcl[(size_t)rm * 256 + cn] = f2bf(acc[i2][j2][r] + bC + pos);
      }
    }
  }
}

// ---------------------------------------------------------------------------
__global__ void k_zero(uint4* __restrict__ p, int n) {
  int i = blockIdx.x * 256 + threadIdx.x;
  if (i < n) p[i] = make_uint4(0u, 0u, 0u, 0u);
}

// ---------------------------------------------------------------------------
__global__ void k_cvt_plain(const float* __restrict__ src, ushort_t* __restrict__ dst, int n4) {
  int i = blockIdx.x * 256 + threadIdx.x;
  if (i >= n4) return;
  float4 v = ((const float4*)src)[i];
  dst[i * 4 + 0] = f2bf(v.x);
  dst[i * 4 + 1] = f2bf(v.y);
  dst[i * 4 + 2] = f2bf(v.z);
  dst[i * 4 + 3] = f2bf(v.w);
}

// wsm_r[n*2304 + t*256 + c] = w_sm[(n*256+c)*9 + t]   (scale-0 weights only)
__global__ void k_cvt_wsm(const float* __restrict__ wsm, ushort_t* __restrict__ dst) {
  int i = blockIdx.x * 256 + threadIdx.x;   // < 256*2304
  int n = i / KP;
  int r = i - n * KP;
  int t = r >> 8, c = r & 255;
  dst[i] = f2bf(wsm[((size_t)(n * 256 + c)) * 9 + t]);
}

// wqr[l][n][c]: n<256 -> w_r1[n][c], else Wq[l][n-256][c]
__global__ void k_cvt_wqr(const float* __restrict__ w_r1, const float* __restrict__ Wq,
                          ushort_t* __restrict__ dst) {
  int i = blockIdx.x * 256 + threadIdx.x;   // < 6*512*256
  if (i >= NL * 512 * 256) return;
  int l = i / (512 * 256);
  int r = i - l * 512 * 256;
  int n = r >> 8, c = r & 255;
  float v = (n < 256) ? w_r1[n * 256 + c] : Wq[((size_t)l * 256 + (n - 256)) * 256 + c];
  dst[i] = f2bf(v);
}

// bqr[l][n]: n<256 -> b_r1[n], else bq[l][n-256]
__global__ void k_bias_qr(const float* __restrict__ b_r1, const float* __restrict__ bq,
                          float* __restrict__ dst) {
  int i = blockIdx.x * 256 + threadIdx.x;   // < 6*512
  if (i >= NL * 512) return;
  int l = i >> 9, n = i & 511;
  dst[i] = (n < 256) ? b_r1[n] : bq[l * 256 + n - 256];
}

// ---------------------------------------------------------------------------
// bf16 MFMA GEMM.  A (M,K) bf16 row-major, W (N,K) bf16 row-major.
// OUTMODE: 0 = fp32 C (bias+ACT)
//          1 = bf16 into padded (B,66,66,256)
//          2 = fp32 C + bf16 mirror Cb, with residual add (res)
//          4 = split: n<256 -> relu -> Cf ; n>=256 -> (float*)Cb  (N=512)
//          5 = relu + mean over groups of 8 m-rows -> bf16 Cb (pvm)
template <int ACT, int OUTMODE, int MG>
__global__ __launch_bounds__(256) void k_gemm_bf16(const ushort_t* __restrict__ A,
                                                   const ushort_t* __restrict__ W,
                                                   const float* __restrict__ bias,
                                                   const float* __restrict__ res,
                                                   float* __restrict__ Cf,
                                                   ushort_t* __restrict__ Cb,
                                                   int M, int N, int K) {
  __shared__ ushort_t As[64 * 40];
  __shared__ ushort_t Bs[64 * 40];
  __shared__ float red[OUTMODE == 5 ? 64 * 65 : 1];
  int tid = threadIdx.x;
  int bm = blockIdx.x * 64, bn = blockIdx.y * 64;
  int w = tid >> 6, lane = tid & 63;
  int wm = (w & 1) * 32, wn = (w >> 1) * 32;
  int q = lane >> 4, ml = lane & 15;
  f32x4 acc[2][2] = {};
  int srow = tid >> 2, scol = (tid & 3) * 8;
  int ga = bm + srow;
  if (MG) ga = min(ga, M - 1);
  const ushort_t* Ag = A + (size_t)ga * K + scol;
  const ushort_t* Wg = W + (size_t)(bn + srow) * K + scol;
  for (int k0 = 0; k0 < K; k0 += 32) {
    short8 av = *(const short8*)(Ag + k0);
    short8 wv = *(const short8*)(Wg + k0);
    *(short8*)(As + srow * 40 + scol) = av;
    *(short8*)(Bs + srow * 40 + scol) = wv;
    __syncthreads();
    short8 a0 = *(const short8*)(As + (wm + ml) * 40 + q * 8);
    short8 a1 = *(const short8*)(As + (wm + 16 + ml) * 40 + q * 8);
    short8 b0 = *(const short8*)(Bs + (wn + ml) * 40 + q * 8);
    short8 b1 = *(const short8*)(Bs + (wn + 16 + ml) * 40 + q * 8);
    acc[0][0] = __builtin_amdgcn_mfma_f32_16x16x32_bf16(a0, b0, acc[0][0], 0, 0, 0);
    acc[0][1] = __builtin_amdgcn_mfma_f32_16x16x32_bf16(a0, b1, acc[0][1], 0, 0, 0);
    acc[1][0] = __builtin_amdgcn_mfma_f32_16x16x32_bf16(a1, b0, acc[1][0], 0, 0, 0);
    acc[1][1] = __builtin_amdgcn_mfma_f32_16x16x32_bf16(a1, b1, acc[1][1], 0, 0, 0);
    __syncthreads();
  }
  if (OUTMODE == 5) {
#pragma unroll
    for (int i = 0; i < 2; ++i)
#pragma unroll
      for (int j = 0; j < 2; ++j) {
        int cn = bn + wn + j * 16 + ml;
        float bsv = bias[cn];
#pragma unroll
        for (int r = 0; r < 4; ++r) {
          int lm = wm + i * 16 + q * 4 + r;
          red[lm * 65 + wn + j * 16 + ml] = fmaxf(acc[i][j][r] + bsv, 0.f);
        }
      }
    __syncthreads();
    for (int idx = tid; idx < 512; idx += 256) {
      int g = idx >> 6, n = idx & 63;
      float sum = 0.f;
#pragma unroll
      for (int r = 0; r < 8; ++r) sum += red[(g * 8 + r) * 65 + n];
      Cb[((size_t)((bm >> 3) + g)) * 256 + bn + n] = f2bf(sum * 0.125f);
    }
    return;
  }
#pragma unroll
  for (int i = 0; i < 2; ++i) {
#pragma unroll
    for (int j = 0; j < 2; ++j) {
      int cn = bn + wn + j * 16 + ml;
      float bsv = bias ? bias[cn] : 0.f;
#pragma unroll
      for (int r = 0; r < 4; ++r) {
        int rm = bm + wm + i * 16 + q * 4 + r;
        if (MG && rm >= M) continue;
        float v = acc[i][j][r] + bsv;
        if (OUTMODE == 0) {
          if (ACT == 1) v = fmaxf(v, 0.f);
          Cf[(size_t)rm * N + cn] = v;
        } else if (OUTMODE == 1) {
          int b = rm >> 12, rem = rm & 4095;
          int y = rem >> 6, xx = rem & 63;
          Cb[(((size_t)(b * 66 + y + 1)) * 66 + xx + 1) * 256 + cn] = f2bf(v);
        } else if (OUTMODE == 2) {
          v += res[(size_t)rm * N + cn];
          Cf[(size_t)rm * N + cn] = v;
          Cb[(size_t)rm * N + cn] = f2bf(v);
        } else if (OUTMODE == 4) {
          if (cn < 256) Cf[(size_t)rm * 256 + cn] = fmaxf(v, 0.f);
          else ((float*)Cb)[(size_t)rm * 256 + cn - 256] = v;
        }
      }
    }
  }
}

// ---------------------------------------------------------------------------
// 3x3 smooth conv as GEMM, A gathered directly from padded x2p (B,66,66,256).
__global__ __launch_bounds__(256) void k_conv3(const ushort_t* __restrict__ x2p,
                                               const ushort_t* __restrict__ wsm,
                                               const float* __restrict__ bsm,
                                               ushort_t* __restrict__ fcl) {
  __shared__ ushort_t As[64 * 40];
  __shared__ ushort_t Bs[64 * 40];
  int tid = threadIdx.x;
  int bm = blockIdx.x * 64, bn = blockIdx.y * 64;
  int b = bm >> 12;
  int s0 = bm & 4095;
  int w = tid >> 6, lane = tid & 63;
  int wm = (w & 1) * 32, wn = (w >> 1) * 32;
  int q = lane >> 4, ml = lane & 15;
  int srow = tid >> 2, scol = (tid & 3) * 8;
  int sA = s0 + srow;
  int ya = sA >> 6, xa = sA & 63;
  size_t pbase = ((size_t)(b * 66 + ya) * 66 + xa) * 256;
  const ushort_t* Wg = wsm + (size_t)(bn + srow) * KP + scol;
  f32x4 acc[2][2] = {};
  for (int t = 0; t < 9; ++t) {
    int ky = t / 3, kx = t - ky * 3;
    size_t aoff = pbase + (size_t)(ky * 66 + kx) * 256 + scol;
#pragma unroll
    for (int c0 = 0; c0 < 256; c0 += 32) {
      short8 av = *(const short8*)(x2p + aoff + c0);
      short8 wv = *(const short8*)(Wg + t * 256 + c0);
      *(short8*)(As + srow * 40 + scol) = av;
      *(short8*)(Bs + srow * 40 + scol) = wv;
      __syncthreads();
      short8 a0 = *(const short8*)(As + (wm + ml) * 40 + q * 8);
      short8 a1 = *(const short8*)(As + (wm + 16 + ml) * 40 + q * 8);
      short8 b0 = *(const short8*)(Bs + (wn + ml) * 40 + q * 8);
      short8 b1 = *(const short8*)(Bs + (wn + 16 + ml) * 40 + q * 8);
      acc[0][0] = __builtin_amdgcn_mfma_f32_16x16x32_bf16(a0, b0, acc[0][0], 0, 0, 0);
      acc[0][1] = __builtin_amdgcn_mfma_f32_16x16x32_bf16(a0, b1, acc[0][1], 0, 0, 0);
      acc[1][0] = __builtin_amdgcn_mfma_f32_16x16x32_bf16(a1, b0, acc[1][0], 0, 0, 0);
      acc[1][1] = __builtin_amdgcn_mfma_f32_16x16x32_bf16(a1, b1, acc[1][1], 0, 0, 0);
      __syncthreads();
    }
  }
#pragma unroll
  for (int i = 0; i < 2; ++i)
#pragma unroll
    for (int j = 0; j < 2; ++j) {
      int cn = bn + wn + j * 16 + ml;
      float bsv = bsm[cn];
#pragma unroll
      for (int r = 0; r < 4; ++r) {
        int rm = bm + wm + i * 16 + q * 4 + r;
        fcl[(size_t)rm * 256 + cn] = f2bf(acc[i][j][r] + bsv);
      }
    }
}

// ---------------------------------------------------------------------------
__global__ void k_init(const float* __restrict__ qe, const float* __restrict__ qp,
                       const float* __restrict__ pb, float* __restrict__ queries,
                       ushort_t* __restrict__ qbf, float* __restrict__ boxes) {
  int i = blockIdx.x * 256 + threadIdx.x;
  if (i < BB * NQ * DM) {
    int rd = i % (NQ * DM);
    float v = qe[rd] + qp[rd];
    queries[i] = v;
    qbf[i] = f2bf(v);
  }
  if (i < BB * NQ * 4) boxes[i] = pb[i];
}

// ---------------------------------------------------------------------------
__global__ void k_r2ref(const float* __restrict__ h1, const float* __restrict__ w_r2,
                        const float* __restrict__ b_r2, const float* __restrict__ boxes,
                        float* __restrict__ ref) {
  int i = blockIdx.x * 256 + threadIdx.x;
  if (i >= BB * NQ * 2 * NP) return;
  int row = i >> 4, o = i & 15;
  const float* hp = h1 + (size_t)row * DM;
  const float* wp = w_r2 + (size_t)o * DM;
  float acc = b_r2[o];
  for (int k = 0; k < DM; ++k) acc += hp[k] * wp[k];
  float ro = 0.5f * tanhf(acc);
  int ax = o & 1;
  float v = boxes[row * 4 + ax] + ro;
  ref[i] = fminf(fmaxf(v, 0.f), 1.f);
}

// ---------------------------------------------------------------------------
// Bilinear patch sampling from channel-last bf16 fcl, writes bf16 flat.
__global__ __launch_bounds__(256) void k_sample(const ushort_t* __restrict__ fcl,
                                                const float* __restrict__ ref,
                                                ushort_t* __restrict__ flat) {
  int blk = blockIdx.x;             // (b*NQ+q)*NP + p
  int c = threadIdx.x;
  int row = blk >> 3;
  int b = row / NQ;
  float rx = ref[blk * 2 + 0];
  float ry = ref[blk * 2 + 1];
  const ushort_t* fb = fcl + (size_t)b * HW * DM;
  ushort_t* op = flat + (size_t)blk * KP;
#pragma unroll
  for (int jy = 0; jy < 3; ++jy) {
    float yy = (ry + (float)(jy - 1) * (1.0f / 64.0f)) * 63.0f;
    yy = fminf(fmaxf(yy, 0.f), 63.0f);
    float y0f = floorf(yy);
    float wy = yy - y0f;
    int y0 = (int)y0f;
    int y1 = min(y0 + 1, 63);
#pragma unroll
    for (int jx = 0; jx < 3; ++jx) {
      float xx = (rx + (float)(jx - 1) * (1.0f / 64.0f)) * 63.0f;
      xx = fminf(fmaxf(xx, 0.f), 63.0f);
      float x0f = floorf(xx);
      float wx = xx - x0f;
      int x0 = (int)x0f;
      int x1 = min(x0 + 1, 63);
      float v00 = bf2f(fb[(y0 * 64 + x0) * DM + c]);
      float v01 = bf2f(fb[(y0 * 64 + x1) * DM + c]);
      float v10 = bf2f(fb[(y1 * 64 + x0) * DM + c]);
      float v11 = bf2f(fb[(y1 * 64 + x1) * DM + c]);
      float v = v00 * (1.f - wx) * (1.f - wy) + v01 * wx * (1.f - wy) +
                v10 * (1.f - wx) * wy + v11 * wx * wy;
      op[(jy * 3 + jx) * DM + c] = f2bf(v);
    }
  }
}

// ---------------------------------------------------------------------------
__global__ __launch_bounds__(256) void k_attn(const float* __restrict__ qb,
                                              const float* __restrict__ kv,
                                              ushort_t* __restrict__ ao) {
  __shared__ float sc[512];
  __shared__ float qs[256];
  __shared__ float red[256];
  int row = blockIdx.x;
  int b = row / NQ;
  int tid = threadIdx.x;
  qs[tid] = qb[(size_t)row * DM + tid];
  __syncthreads();
  const float* kvb = kv + (size_t)b * NQ * DM;
  for (int k = tid; k < 512; k += 256) {
    float v = -1e30f;
    if (k < NQ) {
      const float* kp = kvb + (size_t)k * DM;
      float a = 0.f;
      for (int d = 0; d < DM; ++d) a += qs[d] * kp[d];
      v = a * (1.0f / 16.0f);
    }
    sc[k] = v;
  }
  __syncthreads();
  red[tid] = fmaxf(sc[tid], sc[tid + 256]);
  __syncthreads();
  for (int st = 128; st > 0; st >>= 1) {
    if (tid < st) red[tid] = fmaxf(red[tid], red[tid + st]);
    __syncthreads();
  }
  float mx = red[0];
  __syncthreads();
  float e0 = (tid < NQ) ? expf(sc[tid] - mx) : 0.f;
  float e1 = (tid + 256 < NQ) ? expf(sc[tid + 256] - mx) : 0.f;
  sc[tid] = e0;
  sc[tid + 256] = e1;
  red[tid] = e0 + e1;
  __syncthreads();
  for (int st = 128; st > 0; st >>= 1) {
    if (tid < st) red[tid] += red[tid + st];
    __syncthreads();
  }
  float inv = 1.0f / red[0];
  __syncthreads();
  float acc = 0.f;
  for (int k = 0; k < NQ; ++k) acc += sc[k] * kvb[(size_t)k * DM + tid];
  ao[(size_t)row * DM + tid] = f2bf(acc * inv);
}

// ---------------------------------------------------------------------------
__global__ void k_box(const float* __restrict__ hb, const float* __restrict__ w_b2,
                      const float* __restrict__ b_b2, float* __restrict__ boxes) {
  int i = blockIdx.x * 256 + threadIdx.x;
  if (i >= BB * NQ * 4) return;
  int row = i >> 2, j = i & 3;
  const float* hp = hb + (size_t)row * DM;
  const float* wp = w_b2 + (size_t)j * DM;
  float a = b_b2[j];
  for (int k = 0; k < DM; ++k) a += hp[k] * wp[k];
  float delta = 1.0f / (1.0f + expf(-a));
  float v = boxes[i] + 0.1f * tanhf(delta - 0.5f);
  boxes[i] = fminf(fmaxf(v, 0.f), 1.f);
}

// ---------------------------------------------------------------------------
__global__ void k_final(const float* __restrict__ queries, const float* __restrict__ w_cls,
                        const float* __restrict__ b_cls, const float* __restrict__ boxes,
                        float* __restrict__ out) {
  int i = blockIdx.x * 256 + threadIdx.x;
  if (i < BB * NQ) {
    const float* qp = queries + (size_t)i * DM;
    float a = b_cls[0];
    for (int k = 0; k < DM; ++k) a += qp[k] * w_cls[k];
    out[i] = a;
  }
  if (i < BB * NQ * 4) out[BB * NQ + i] = boxes[i];
}

// ---------------------------------------------------------------------------
extern "C" void kernel_launch(void* const* d_in, const int* in_sizes, int n_in,
                              void* d_out, int out_size, void* d_ws, size_t ws_size,
                              hipStream_t stream) {
  const float* feat   = (const float*)d_in[0];
  const float* pb     = (const float*)d_in[1];
  const float* w_tf   = (const float*)d_in[2];
  const float* b_tf   = (const float*)d_in[3];
  const float* w_in   = (const float*)d_in[4];
  const float* b_in   = (const float*)d_in[5];
  const float* w_lat  = (const float*)d_in[6];
  const float* b_lat  = (const float*)d_in[7];
  const float* w_sm   = (const float*)d_in[8];
  const float* b_sm   = (const float*)d_in[9];
  const float* q_embed= (const float*)d_in[10];
  const float* q_pos  = (const float*)d_in[11];
  const float* Wq     = (const float*)d_in[12];
  const float* bq     = (const float*)d_in[13];
  const float* Wo     = (const float*)d_in[14];
  const float* bo     = (const float*)d_in[15];
  const float* Wp1    = (const float*)d_in[16];
  const float* bp1    = (const float*)d_in[17];
  const float* Wp2    = (const float*)d_in[18];
  const float* bp2    = (const float*)d_in[19];
  const float* w_r1   = (const float*)d_in[20];
  const float* b_r1   = (const float*)d_in[21];
  const float* w_r2   = (const float*)d_in[22];
  const float* b_r2   = (const float*)d_in[23];
  const float* w_b1   = (const float*)d_in[24];
  const float* b_b1   = (const float*)d_in[25];
  const float* w_b2   = (const float*)d_in[26];
  const float* b_b2   = (const float*)d_in[27];
  const float* w_cls  = (const float*)d_in[28];
  const float* b_cls  = (const float*)d_in[29];
  float* out = (float*)d_out;

  float* ws = (float*)d_ws;
  size_t off = 0;
  auto alloc = [&](size_t n) { float* p = ws + off; off += n; return p; };
  ushort_t* flat    = (ushort_t*)alloc(5529600);   // 4800 x 2304 bf16
  ushort_t* xcl     = (ushort_t*)alloc(1048576);   // 8192 x 256 bf16
  ushort_t* x2p     = (ushort_t*)alloc(1115136);   // 2 x 66 x 66 x 256 bf16
  ushort_t* fcl     = (ushort_t*)alloc(1048576);   // 8192 x 256 bf16
  ushort_t* wcomb   = (ushort_t*)alloc(65536);     // 256 x 512 bf16
  float*    biasc   = alloc(256);
  ushort_t* wlat_bf = (ushort_t*)alloc(32768);
  ushort_t* wsm_bf  = (ushort_t*)alloc(294912);
  ushort_t* wp1_bf  = (ushort_t*)alloc(1769472);   // 6 x 256 x 2304
  ushort_t* wqr_bf  = (ushort_t*)alloc(393216);    // 6 x 512 x 256
  float*    bqr     = alloc(3072);                 // 6 x 512
  ushort_t* wp2_bf  = (ushort_t*)alloc(196608);    // 6 x 256 x 256
  ushort_t* wo_bf   = (ushort_t*)alloc(196608);
  ushort_t* wb1_bf  = (ushort_t*)alloc(32768);
  float* queries = alloc(153600);
  ushort_t* qbf  = (ushort_t*)alloc(76800);
  float* h1      = alloc(153600);
  float* qbuf    = alloc(153600);
  float* kv      = alloc(153600);
  ushort_t* ao   = (ushort_t*)alloc(76800);
  float* hb      = alloc(153600);
  ushort_t* pvm  = (ushort_t*)alloc(76800);
  float* boxes   = alloc(2400);
  float* ref     = alloc(9600);
  (void)ws_size; (void)in_sizes; (void)n_in; (void)out_size;

  // --- weight prep (independent) ---
  k_wcomb<<<256, 512, 0, stream>>>(w_tf, b_tf, w_in, b_in, wcomb, biasc);
  k_cvt_plain<<<64, 256, 0, stream>>>(w_lat, wlat_bf, 16384);
  k_cvt_wsm<<<2304, 256, 0, stream>>>(w_sm, wsm_bf);
  k_cvt_plain<<<3456, 256, 0, stream>>>(Wp1, wp1_bf, 884736);
  k_cvt_wqr<<<3072, 256, 0, stream>>>(w_r1, Wq, wqr_bf);
  k_bias_qr<<<12, 256, 0, stream>>>(b_r1, bq, bqr);
  k_cvt_plain<<<384, 256, 0, stream>>>(Wp2, wp2_bf, 98304);
  k_cvt_plain<<<384, 256, 0, stream>>>(Wo, wo_bf, 98304);
  // BUGFIX (round 3): w_b1 is 256x256 = 65536 floats = 16384 float4, not 4096.
  k_cvt_plain<<<64, 256, 0, stream>>>(w_b1, wb1_bf, 16384);
  k_zero<<<1089, 256, 0, stream>>>((uint4*)x2p, 278784);

  // --- backbone ---
  k_feat<<<dim3(128, 4), 256, 0, stream>>>(feat, wcomb, biasc, xcl);
  k_gemm_bf16<0, 1, 0><<<dim3(128, 4), 256, 0, stream>>>(xcl, wlat_bf, b_lat, nullptr,
                                                         nullptr, x2p, BB * HW, 256, 256);
  k_conv3<<<dim3(128, 4), 256, 0, stream>>>(x2p, wsm_bf, b_sm, fcl);
  k_init<<<600, 256, 0, stream>>>(q_embed, q_pos, pb, queries, qbf, boxes);

  const int M6 = BB * NQ;                 // 600
  const int Mp = BB * NQ * NP;            // 4800
  dim3 g600((M6 + 63) / 64, 4);           // (10,4)
  dim3 g600w((M6 + 63) / 64, 8);          // (10,8) for merged N=512
  dim3 gp(Mp / 64, 4);                    // (75,4)

  for (int l = 0; l < NL; ++l) {
    // merged h1 (relu) | qbuf GEMM on queries
    k_gemm_bf16<0, 4, 1><<<g600w, 256, 0, stream>>>(qbf, wqr_bf + (size_t)l * 512 * 256,
                                                    bqr + l * 512, nullptr, h1,
                                                    (ushort_t*)qbuf, M6, 512, 256);
    k_r2ref<<<(M6 * 16 + 255) / 256, 256, 0, stream>>>(h1, w_r2, b_r2, boxes, ref);
    k_sample<<<Mp, 256, 0, stream>>>(fcl, ref, flat);
    // Wp1 GEMM + fused relu+pmean -> pvm bf16
    k_gemm_bf16<0, 5, 0><<<gp, 256, 0, stream>>>(flat, wp1_bf + (size_t)l * 256 * KP,
                                                 bp1 + (size_t)l * DM, nullptr, nullptr,
                                                 pvm, Mp, DM, KP);
    // kv = pvm @ Wp2 + bp2
    k_gemm_bf16<0, 0, 1><<<g600, 256, 0, stream>>>(pvm, wp2_bf + (size_t)l * DM * DM,
                                                   bp2 + (size_t)l * DM, nullptr, kv,
                                                   nullptr, M6, DM, DM);
    k_attn<<<M6, 256, 0, stream>>>(qbuf, kv, ao);
    // queries += ao @ Wo + bo   (fp32 master + bf16 mirror)
    k_gemm_bf16<0, 2, 1><<<g600, 256, 0, stream>>>(ao, wo_bf + (size_t)l * DM * DM,
                                                   bo + (size_t)l * DM, queries, queries,
                                                   qbf, M6, DM, DM);
    // hb = relu(queries @ w_b1 + b_b1)
    k_gemm_bf16<1, 0, 1><<<g600, 256, 0, stream>>>(qbf, wb1_bf, b_b1, nullptr, hb,
                                                   nullptr, M6, DM, DM);
    k_box<<<(M6 * 4 + 255) / 256, 256, 0, stream>>>(hb, w_b2, b_b2, boxes);
  }
  k_final<<<(BB * NQ * 4 + 255) / 256, 256, 0, stream>>>(queries, w_cls, b_cls, boxes, out);
}

// Round 5
// 957.900 us; speedup vs baseline: 2.8496x; 1.1036x over previous
//
#include <hip/hip_runtime.h>
#include <hip/hip_bf16.h>
#include <math.h>

// Problem constants
#define BB 2
#define TT 4
#define CIN 128
#define DM 256
#define NQ 300
#define NP 8
#define PS 3
#define NL 6
#define HW 4096   // 64*64
#define KP 2304   // 3*3*256

typedef __attribute__((ext_vector_type(8))) short short8;
typedef __attribute__((ext_vector_type(4))) float f32x4;
typedef unsigned short ushort_t;

static __device__ __forceinline__ ushort_t f2bf(float f) {
  __hip_bfloat16 h = __float2bfloat16(f);
  return *reinterpret_cast<ushort_t*>(&h);
}
static __device__ __forceinline__ float bf2f(ushort_t u) {
  return __uint_as_float(((unsigned)u) << 16);
}

// ---------------------------------------------------------------------------
// Temporal-conv coefficient matrix, transposed for GEMM:
// tct[k][c] with k = u*128+ci:  0.25 * tc(c,ci,u)
// tc: u=0 -> w0+w1 ; u=1,2 -> w0+w1+w2 ; u=3 -> w1+w2   (w* = w_tf[c,ci,*])
__global__ void k_tc(const float* __restrict__ w_tf, ushort_t* __restrict__ tct) {
  int i = blockIdx.x * 256 + threadIdx.x;   // < 512*128
  int k = i >> 7, c = i & 127;
  int u = k >> 7;
  int ci = k & 127;
  const float* wp = w_tf + ((size_t)(c * 128 + ci)) * 3;
  float w0 = wp[0], w1 = wp[1], w2 = wp[2];
  float coef = (u == 0) ? (w0 + w1) : (u == 3) ? (w1 + w2) : (w0 + w1 + w2);
  tct[(size_t)k * 128 + c] = f2bf(0.25f * coef);
}

// bias_comb[d] = b_in[d] + sum_c w_in[d,c]*b_tf[c]   (1 block, 256 threads)
__global__ void k_bcomb(const float* __restrict__ w_in, const float* __restrict__ b_tf,
                        const float* __restrict__ b_in, float* __restrict__ bias_comb) {
  __shared__ float bt[128];
  int d = threadIdx.x;
  if (d < 128) bt[d] = b_tf[d];
  __syncthreads();
  float a = b_in[d];
  for (int c = 0; c < 128; ++c) a += w_in[d * 128 + c] * bt[c];
  bias_comb[d] = a;
}

// ---------------------------------------------------------------------------
// Fused backbone GEMM: xcl[b*HW+s][d] = bf16( feat_t[s][:] . Wcomb[d][:] +
//                                             bias_comb[d] + pos(d, y, x) )
__global__ __launch_bounds__(256) void k_feat(const float* __restrict__ feat,
                                              const ushort_t* __restrict__ wcomb,
                                              const float* __restrict__ bias_comb,
                                              ushort_t* __restrict__ xcl) {
  __shared__ ushort_t As[64 * 40];
  __shared__ ushort_t Bs[64 * 40];
  __shared__ float dimt_s[256];
  int tid = threadIdx.x;
  {
    int dd = tid & 127;
    int ii = dd >> 1;
    float e = (2.0f * (float)(ii >> 1)) / 64.0f;
    dimt_s[tid] = powf(10000.0f, e);
  }
  int bm = blockIdx.x * 64, bn = blockIdx.y * 64;
  int b = bm >> 12;
  int s0 = bm & 4095;
  int w = tid >> 6, lane = tid & 63;
  int wm = (w & 1) * 32, wn = (w >> 1) * 32;
  int q = lane >> 4, ml = lane & 15;
  int srow = tid >> 2, scol = (tid & 3) * 8;
  const ushort_t* Wg = wcomb + (size_t)(bn + srow) * 512 + scol;
  f32x4 acc[2][2] = {};
  for (int k0 = 0; k0 < 512; k0 += 32) {
    short8 wv = *(const short8*)(Wg + k0);
#pragma unroll
    for (int j = 0; j < 8; ++j) {
      int kk = w * 8 + j;
      int k = k0 + kk;
      int u = k >> 7, ci = k & 127;
      float v = feat[(((size_t)(b * 4 + u) * 128 + ci) << 12) + s0 + lane];
      As[lane * 40 + kk] = f2bf(v);
    }
    *(short8*)(Bs + srow * 40 + scol) = wv;
    __syncthreads();
    short8 a0 = *(const short8*)(As + (wm + ml) * 40 + q * 8);
    short8 a1 = *(const short8*)(As + (wm + 16 + ml) * 40 + q * 8);
    short8 b0 = *(const short8*)(Bs + (wn + ml) * 40 + q * 8);
    short8 b1 = *(const short8*)(Bs + (wn + 16 + ml) * 40 + q * 8);
    acc[0][0] = __builtin_amdgcn_mfma_f32_16x16x32_bf16(a0, b0, acc[0][0], 0, 0, 0);
    acc[0][1] = __builtin_amdgcn_mfma_f32_16x16x32_bf16(a0, b1, acc[0][1], 0, 0, 0);
    acc[1][0] = __builtin_amdgcn_mfma_f32_16x16x32_bf16(a1, b0, acc[1][0], 0, 0, 0);
    acc[1][1] = __builtin_amdgcn_mfma_f32_16x16x32_bf16(a1, b1, acc[1][1], 0, 0, 0);
    __syncthreads();
  }
  const float FKT = 6.28318530717958647692f / 64.000001f;
#pragma unroll
  for (int i2 = 0; i2 < 2; ++i2) {
#pragma unroll
    for (int j2 = 0; j2 < 2; ++j2) {
      int cn = bn + wn + j2 * 16 + ml;
      float dimt = dimt_s[cn];
      float bC = bias_comb[cn];
      bool isx = cn >= 128;
      bool isc = cn & 1;
#pragma unroll
      for (int r = 0; r < 4; ++r) {
        int rm = bm + wm + i2 * 16 + q * 4 + r;
        int s = rm & 4095;
        int y = s >> 6, x = s & 63;
        float ang = (float)((isx ? x : y) + 1) * FKT / dimt;
        float pos = isc ? cosf(ang) : sinf(ang);
        xcl[(size_t)rm * 256 + cn] = f2bf(acc[i2][j2][r] + bC + pos);
      }
    }
  }
}

// ---------------------------------------------------------------------------
__global__ void k_zero(uint4* __restrict__ p, int n) {
  int i = blockIdx.x * 256 + threadIdx.x;
  if (i < n) p[i] = make_uint4(0u, 0u, 0u, 0u);
}

// ---------------------------------------------------------------------------
// ALL plain fp32->bf16 weight converts in one launch. Segment bounds in float4:
// w_in 8192 | w_lat 16384 | Wp2 98304 | Wo 98304 | w_b1 16384 | Wp1 884736
__global__ void k_cvt_all(const float* __restrict__ s0, const float* __restrict__ s1,
                          const float* __restrict__ s2, const float* __restrict__ s3,
                          const float* __restrict__ s4, const float* __restrict__ s5,
                          ushort_t* __restrict__ d0, ushort_t* __restrict__ d1,
                          ushort_t* __restrict__ d2, ushort_t* __restrict__ d3,
                          ushort_t* __restrict__ d4, ushort_t* __restrict__ d5) {
  int i = blockIdx.x * 256 + threadIdx.x;
  const float* s; ushort_t* d; int base;
  if (i < 8192)         { s = s0; d = d0; base = 0; }
  else if (i < 24576)   { s = s1; d = d1; base = 8192; }
  else if (i < 122880)  { s = s2; d = d2; base = 24576; }
  else if (i < 221184)  { s = s3; d = d3; base = 122880; }
  else if (i < 237568)  { s = s4; d = d4; base = 221184; }
  else if (i < 1122304) { s = s5; d = d5; base = 237568; }
  else return;
  int j = i - base;
  float4 v = ((const float4*)s)[j];
  d[j * 4 + 0] = f2bf(v.x);
  d[j * 4 + 1] = f2bf(v.y);
  d[j * 4 + 2] = f2bf(v.z);
  d[j * 4 + 3] = f2bf(v.w);
}

// wsm_r[n*2304 + t*256 + c] = w_sm[(n*256+c)*9 + t]   (scale-0 weights only)
__global__ void k_cvt_wsm(const float* __restrict__ wsm, ushort_t* __restrict__ dst) {
  int i = blockIdx.x * 256 + threadIdx.x;   // < 256*2304
  int n = i / KP;
  int r = i - n * KP;
  int t = r >> 8, c = r & 255;
  dst[i] = f2bf(wsm[((size_t)(n * 256 + c)) * 9 + t]);
}

// wqr[l][n][c]: n<256 -> w_r1[n][c], else Wq[l][n-256][c]
__global__ void k_cvt_wqr(const float* __restrict__ w_r1, const float* __restrict__ Wq,
                          ushort_t* __restrict__ dst) {
  int i = blockIdx.x * 256 + threadIdx.x;   // < 6*512*256
  if (i >= NL * 512 * 256) return;
  int l = i / (512 * 256);
  int r = i - l * 512 * 256;
  int n = r >> 8, c = r & 255;
  float v = (n < 256) ? w_r1[n * 256 + c] : Wq[((size_t)l * 256 + (n - 256)) * 256 + c];
  dst[i] = f2bf(v);
}

// bqr[l][n]: n<256 -> b_r1[n], else bq[l][n-256]
__global__ void k_bias_qr(const float* __restrict__ b_r1, const float* __restrict__ bq,
                          float* __restrict__ dst) {
  int i = blockIdx.x * 256 + threadIdx.x;   // < 6*512
  if (i >= NL * 512) return;
  int l = i >> 9, n = i & 511;
  dst[i] = (n < 256) ? b_r1[n] : bq[l * 256 + n - 256];
}

// ---------------------------------------------------------------------------
// bf16 MFMA GEMM, BM=BN=64, BK=32.  A (M,K), W (N,K) bf16 row-major.
// OUTMODE: 0 = fp32 C (bias+ACT)
//          1 = bf16 into padded (B,66,66,256)
//          2 = fp32 C + bf16 mirror Cb, with residual add (res)
//          4 = split: n<256 -> relu -> Cf ; n>=256 -> (float*)Cb  (N=512)
//          6 = plain bf16 out Cb (row-major M x N)
template <int ACT, int OUTMODE, int MG>
__global__ __launch_bounds__(256) void k_gemm_bf16(const ushort_t* __restrict__ A,
                                                   const ushort_t* __restrict__ W,
                                                   const float* __restrict__ bias,
                                                   const float* __restrict__ res,
                                                   float* __restrict__ Cf,
                                                   ushort_t* __restrict__ Cb,
                                                   int M, int N, int K) {
  __shared__ ushort_t As[64 * 40];
  __shared__ ushort_t Bs[64 * 40];
  int tid = threadIdx.x;
  int bm = blockIdx.x * 64, bn = blockIdx.y * 64;
  int w = tid >> 6, lane = tid & 63;
  int wm = (w & 1) * 32, wn = (w >> 1) * 32;
  int q = lane >> 4, ml = lane & 15;
  f32x4 acc[2][2] = {};
  int srow = tid >> 2, scol = (tid & 3) * 8;
  int ga = bm + srow;
  if (MG) ga = min(ga, M - 1);
  const ushort_t* Ag = A + (size_t)ga * K + scol;
  const ushort_t* Wg = W + (size_t)(bn + srow) * K + scol;
  for (int k0 = 0; k0 < K; k0 += 32) {
    short8 av = *(const short8*)(Ag + k0);
    short8 wv = *(const short8*)(Wg + k0);
    *(short8*)(As + srow * 40 + scol) = av;
    *(short8*)(Bs + srow * 40 + scol) = wv;
    __syncthreads();
    short8 a0 = *(const short8*)(As + (wm + ml) * 40 + q * 8);
    short8 a1 = *(const short8*)(As + (wm + 16 + ml) * 40 + q * 8);
    short8 b0 = *(const short8*)(Bs + (wn + ml) * 40 + q * 8);
    short8 b1 = *(const short8*)(Bs + (wn + 16 + ml) * 40 + q * 8);
    acc[0][0] = __builtin_amdgcn_mfma_f32_16x16x32_bf16(a0, b0, acc[0][0], 0, 0, 0);
    acc[0][1] = __builtin_amdgcn_mfma_f32_16x16x32_bf16(a0, b1, acc[0][1], 0, 0, 0);
    acc[1][0] = __builtin_amdgcn_mfma_f32_16x16x32_bf16(a1, b0, acc[1][0], 0, 0, 0);
    acc[1][1] = __builtin_amdgcn_mfma_f32_16x16x32_bf16(a1, b1, acc[1][1], 0, 0, 0);
    __syncthreads();
  }
#pragma unroll
  for (int i = 0; i < 2; ++i) {
#pragma unroll
    for (int j = 0; j < 2; ++j) {
      int cn = bn + wn + j * 16 + ml;
      float bsv = bias ? bias[cn] : 0.f;
#pragma unroll
      for (int r = 0; r < 4; ++r) {
        int rm = bm + wm + i * 16 + q * 4 + r;
        if (MG && rm >= M) continue;
        float v = acc[i][j][r] + bsv;
        if (OUTMODE == 0) {
          if (ACT == 1) v = fmaxf(v, 0.f);
          Cf[(size_t)rm * N + cn] = v;
        } else if (OUTMODE == 1) {
          int b = rm >> 12, rem = rm & 4095;
          int y = rem >> 6, xx = rem & 63;
          Cb[(((size_t)(b * 66 + y + 1)) * 66 + xx + 1) * 256 + cn] = f2bf(v);
        } else if (OUTMODE == 2) {
          v += res[(size_t)rm * N + cn];
          Cf[(size_t)rm * N + cn] = v;
          Cb[(size_t)rm * N + cn] = f2bf(v);
        } else if (OUTMODE == 4) {
          if (cn < 256) Cf[(size_t)rm * 256 + cn] = fmaxf(v, 0.f);
          else ((float*)Cb)[(size_t)rm * 256 + cn - 256] = v;
        } else if (OUTMODE == 6) {
          Cb[(size_t)rm * N + cn] = f2bf(v);
        }
      }
    }
  }
}

// ---------------------------------------------------------------------------
// Big-tile bf16 MFMA GEMM: BM=128, BN=64, BK=32, 256 threads (4 waves 64x32).
// K must be KP=2304-style (any multiple of 32 works for GATHER=0).
// GATHER: 0 = A is (M,K) rows (clamped for partial last tile)
//         1 = A gathered from padded x2p (B,66,66,256); k = tap*256 + c
// OUT:    0 = relu + mean over groups of 8 m-rows -> Cb (600 x 256) [Wp1+pmean]
//         1 = plain bf16 out + bias -> Cb (M x 256)                 [conv3]
template <int GATHER, int OUT>
__global__ __launch_bounds__(256) void k_gemm128(const ushort_t* __restrict__ A,
                                                 const ushort_t* __restrict__ W,
                                                 const float* __restrict__ bias,
                                                 ushort_t* __restrict__ Cb,
                                                 int M, int K) {
  __shared__ char smem_raw[33280];           // staging 15360 B / red 33280 B
  ushort_t* As = (ushort_t*)smem_raw;        // 128*40
  ushort_t* Bs = As + 128 * 40;              // 64*40
  float* red = (float*)smem_raw;             // 128*65 (reuse after k-loop)
  int tid = threadIdx.x;
  int bm = blockIdx.x * 128, bn = blockIdx.y * 64;
  int w = tid >> 6, lane = tid & 63;
  int wr = (w >> 1) * 64, wc = (w & 1) * 32;
  int q = lane >> 4, ml = lane & 15;
  f32x4 acc[4][2] = {};
  int ar0 = tid >> 2, ac0 = (tid & 3) * 8;
  int ar1 = ar0 + 64, ac1 = ac0;
  int br = tid >> 2, bc = (tid & 3) * 8;
  const ushort_t* Wg = W + (size_t)(bn + br) * K + bc;
  const ushort_t* Ag0 = nullptr;
  const ushort_t* Ag1 = nullptr;
  size_t pb0 = 0, pb1 = 0;
  if (GATHER == 0) {
    int r0 = min(bm + ar0, M - 1), r1 = min(bm + ar1, M - 1);
    Ag0 = A + (size_t)r0 * K + ac0;
    Ag1 = A + (size_t)r1 * K + ac1;
  } else {
    int s0g = bm + ar0;
    int b0 = s0g >> 12, rem0 = s0g & 4095;
    pb0 = ((size_t)(b0 * 66 + (rem0 >> 6)) * 66 + (rem0 & 63)) * 256 + ac0;
    int s1g = bm + ar1;
    int b1 = s1g >> 12, rem1 = s1g & 4095;
    pb1 = ((size_t)(b1 * 66 + (rem1 >> 6)) * 66 + (rem1 & 63)) * 256 + ac1;
  }
  for (int k0 = 0; k0 < K; k0 += 32) {
    short8 av0, av1;
    if (GATHER == 0) {
      av0 = *(const short8*)(Ag0 + k0);
      av1 = *(const short8*)(Ag1 + k0);
    } else {
      int t = k0 >> 8;
      int ky = t / 3, kx = t - ky * 3;
      size_t toff = (size_t)(ky * 66 + kx) * 256 + (k0 & 255);
      av0 = *(const short8*)(A + pb0 + toff);
      av1 = *(const short8*)(A + pb1 + toff);
    }
    short8 wv = *(const short8*)(Wg + k0);
    *(short8*)(As + ar0 * 40 + ac0) = av0;
    *(short8*)(As + ar1 * 40 + ac1) = av1;
    *(short8*)(Bs + br * 40 + bc) = wv;
    __syncthreads();
    short8 b0v = *(const short8*)(Bs + (wc + ml) * 40 + q * 8);
    short8 b1v = *(const short8*)(Bs + (wc + 16 + ml) * 40 + q * 8);
#pragma unroll
    for (int i = 0; i < 4; ++i) {
      short8 a = *(const short8*)(As + (wr + i * 16 + ml) * 40 + q * 8);
      acc[i][0] = __builtin_amdgcn_mfma_f32_16x16x32_bf16(a, b0v, acc[i][0], 0, 0, 0);
      acc[i][1] = __builtin_amdgcn_mfma_f32_16x16x32_bf16(a, b1v, acc[i][1], 0, 0, 0);
    }
    __syncthreads();
  }
  if (OUT == 1) {
#pragma unroll
    for (int i = 0; i < 4; ++i)
#pragma unroll
      for (int j = 0; j < 2; ++j) {
        int cn = bn + wc + j * 16 + ml;
        float bsv = bias[cn];
#pragma unroll
        for (int r = 0; r < 4; ++r) {
          int rm = bm + wr + i * 16 + q * 4 + r;
          Cb[(size_t)rm * 256 + cn] = f2bf(acc[i][j][r] + bsv);
        }
      }
    return;
  }
  // OUT==0: relu + pmean over groups of 8 rows -> Cb (600 x 256)
  __syncthreads();
#pragma unroll
  for (int i = 0; i < 4; ++i)
#pragma unroll
    for (int j = 0; j < 2; ++j) {
      int cl = wc + j * 16 + ml;
      float bsv = bias[bn + cl];
#pragma unroll
      for (int r = 0; r < 4; ++r) {
        int rl = wr + i * 16 + q * 4 + r;
        red[rl * 65 + cl] = fmaxf(acc[i][j][r] + bsv, 0.f);
      }
    }
  __syncthreads();
  for (int idx = tid; idx < 16 * 64; idx += 256) {
    int g = idx >> 6, n = idx & 63;
    int grow = (bm >> 3) + g;
    if (grow < 600) {
      float s = 0.f;
#pragma unroll
      for (int r = 0; r < 8; ++r) s += red[(g * 8 + r) * 65 + n];
      Cb[(size_t)grow * 256 + bn + n] = f2bf(s * 0.125f);
    }
  }
}

// ---------------------------------------------------------------------------
__global__ void k_init(const float* __restrict__ qe, const float* __restrict__ qp,
                       const float* __restrict__ pb, float* __restrict__ queries,
                       ushort_t* __restrict__ qbf, float* __restrict__ boxes) {
  int i = blockIdx.x * 256 + threadIdx.x;
  if (i < BB * NQ * DM) {
    int rd = i % (NQ * DM);
    float v = qe[rd] + qp[rd];
    queries[i] = v;
    qbf[i] = f2bf(v);
  }
  if (i < BB * NQ * 4) boxes[i] = pb[i];
}

// ---------------------------------------------------------------------------
// Fused r2ref + bilinear patch sampling. Block per (b,q,p); thread = channel.
__global__ __launch_bounds__(256) void k_sample(const ushort_t* __restrict__ fcl,
                                                const float* __restrict__ h1,
                                                const float* __restrict__ w_r2,
                                                const float* __restrict__ b_r2,
                                                const float* __restrict__ boxes,
                                                ushort_t* __restrict__ flat) {
  __shared__ float pr[8];
  __shared__ float bc2[2];
  int blk = blockIdx.x;             // (b*NQ+q)*NP + p
  int row = blk >> 3, p = blk & 7;
  int b = row / NQ;
  int tid = threadIdx.x;
  // ref computation: rx = clip(box_x + 0.5*tanh(h1 . w_r2[2p] + b), 0, 1)
  float h = h1[(size_t)row * 256 + tid];
  float px = h * w_r2[(size_t)(2 * p) * 256 + tid];
  float py = h * w_r2[(size_t)(2 * p + 1) * 256 + tid];
#pragma unroll
  for (int s = 32; s > 0; s >>= 1) {
    px += __shfl_down(px, s, 64);
    py += __shfl_down(py, s, 64);
  }
  int w = tid >> 6, lane = tid & 63;
  if (lane == 0) { pr[w * 2] = px; pr[w * 2 + 1] = py; }
  __syncthreads();
  if (tid == 0) {
    float sx = pr[0] + pr[2] + pr[4] + pr[6] + b_r2[2 * p];
    float sy = pr[1] + pr[3] + pr[5] + pr[7] + b_r2[2 * p + 1];
    float rx = boxes[row * 4 + 0] + 0.5f * tanhf(sx);
    float ry = boxes[row * 4 + 1] + 0.5f * tanhf(sy);
    bc2[0] = fminf(fmaxf(rx, 0.f), 1.f);
    bc2[1] = fminf(fmaxf(ry, 0.f), 1.f);
  }
  __syncthreads();
  float rx = bc2[0], ry = bc2[1];
  int c = tid;
  const ushort_t* fb = fcl + (size_t)b * HW * DM;
  ushort_t* op = flat + (size_t)blk * KP;
#pragma unroll
  for (int jy = 0; jy < 3; ++jy) {
    float yy = (ry + (float)(jy - 1) * (1.0f / 64.0f)) * 63.0f;
    yy = fminf(fmaxf(yy, 0.f), 63.0f);
    float y0f = floorf(yy);
    float wy = yy - y0f;
    int y0 = (int)y0f;
    int y1 = min(y0 + 1, 63);
#pragma unroll
    for (int jx = 0; jx < 3; ++jx) {
      float xx = (rx + (float)(jx - 1) * (1.0f / 64.0f)) * 63.0f;
      xx = fminf(fmaxf(xx, 0.f), 63.0f);
      float x0f = floorf(xx);
      float wx = xx - x0f;
      int x0 = (int)x0f;
      int x1 = min(x0 + 1, 63);
      float v00 = bf2f(fb[(y0 * 64 + x0) * DM + c]);
      float v01 = bf2f(fb[(y0 * 64 + x1) * DM + c]);
      float v10 = bf2f(fb[(y1 * 64 + x0) * DM + c]);
      float v11 = bf2f(fb[(y1 * 64 + x1) * DM + c]);
      float v = v00 * (1.f - wx) * (1.f - wy) + v01 * wx * (1.f - wy) +
                v10 * (1.f - wx) * wy + v11 * wx * wy;
      op[(jy * 3 + jx) * DM + c] = f2bf(v);
    }
  }
}

// ---------------------------------------------------------------------------
__global__ __launch_bounds__(256) void k_attn(const float* __restrict__ qb,
                                              const float* __restrict__ kv,
                                              ushort_t* __restrict__ ao) {
  __shared__ float sc[512];
  __shared__ float qs[256];
  __shared__ float red[256];
  int row = blockIdx.x;
  int b = row / NQ;
  int tid = threadIdx.x;
  qs[tid] = qb[(size_t)row * DM + tid];
  __syncthreads();
  const float* kvb = kv + (size_t)b * NQ * DM;
  for (int k = tid; k < 512; k += 256) {
    float v = -1e30f;
    if (k < NQ) {
      const float* kp = kvb + (size_t)k * DM;
      float a = 0.f;
      for (int d = 0; d < DM; ++d) a += qs[d] * kp[d];
      v = a * (1.0f / 16.0f);
    }
    sc[k] = v;
  }
  __syncthreads();
  red[tid] = fmaxf(sc[tid], sc[tid + 256]);
  __syncthreads();
  for (int st = 128; st > 0; st >>= 1) {
    if (tid < st) red[tid] = fmaxf(red[tid], red[tid + st]);
    __syncthreads();
  }
  float mx = red[0];
  __syncthreads();
  float e0 = (tid < NQ) ? expf(sc[tid] - mx) : 0.f;
  float e1 = (tid + 256 < NQ) ? expf(sc[tid + 256] - mx) : 0.f;
  sc[tid] = e0;
  sc[tid + 256] = e1;
  red[tid] = e0 + e1;
  __syncthreads();
  for (int st = 128; st > 0; st >>= 1) {
    if (tid < st) red[tid] += red[tid + st];
    __syncthreads();
  }
  float inv = 1.0f / red[0];
  __syncthreads();
  float acc = 0.f;
  for (int k = 0; k < NQ; ++k) acc += sc[k] * kvb[(size_t)k * DM + tid];
  ao[(size_t)row * DM + tid] = f2bf(acc * inv);
}

// ---------------------------------------------------------------------------
// box update: block per row; wave j computes dot(hb[row], w_b2[j]) via shuffle.
__global__ __launch_bounds__(256) void k_box(const float* __restrict__ hb,
                                             const float* __restrict__ w_b2,
                                             const float* __restrict__ b_b2,
                                             float* __restrict__ boxes) {
  int row = blockIdx.x;
  int tid = threadIdx.x;
  int j = tid >> 6, lane = tid & 63;
  float4 hv = *(const float4*)(hb + (size_t)row * 256 + lane * 4);
  float4 wv = *(const float4*)(w_b2 + (size_t)j * 256 + lane * 4);
  float aa = hv.x * wv.x + hv.y * wv.y + hv.z * wv.z + hv.w * wv.w;
#pragma unroll
  for (int s = 32; s > 0; s >>= 1) aa += __shfl_down(aa, s, 64);
  if (lane == 0) {
    aa += b_b2[j];
    float delta = 1.0f / (1.0f + expf(-aa));
    float v = boxes[row * 4 + j] + 0.1f * tanhf(delta - 0.5f);
    boxes[row * 4 + j] = fminf(fmaxf(v, 0.f), 1.f);
  }
}

// ---------------------------------------------------------------------------
__global__ __launch_bounds__(256) void k_final(const float* __restrict__ queries,
                                               const float* __restrict__ w_cls,
                                               const float* __restrict__ b_cls,
                                               const float* __restrict__ boxes,
                                               float* __restrict__ out) {
  int row = blockIdx.x;   // 600
  int tid = threadIdx.x;
  int w = tid >> 6, lane = tid & 63;
  if (w == 0) {
    float4 qv = *(const float4*)(queries + (size_t)row * 256 + lane * 4);
    float4 wv = *(const float4*)(w_cls + lane * 4);
    float aa = qv.x * wv.x + qv.y * wv.y + qv.z * wv.z + qv.w * wv.w;
#pragma unroll
    for (int s = 32; s > 0; s >>= 1) aa += __shfl_down(aa, s, 64);
    if (lane == 0) out[row] = aa + b_cls[0];
  } else if (w == 1 && lane < 4) {
    out[600 + row * 4 + lane] = boxes[row * 4 + lane];
  }
}

// ---------------------------------------------------------------------------
extern "C" void kernel_launch(void* const* d_in, const int* in_sizes, int n_in,
                              void* d_out, int out_size, void* d_ws, size_t ws_size,
                              hipStream_t stream) {
  const float* feat   = (const float*)d_in[0];
  const float* pb     = (const float*)d_in[1];
  const float* w_tf   = (const float*)d_in[2];
  const float* b_tf   = (const float*)d_in[3];
  const float* w_in   = (const float*)d_in[4];
  const float* b_in   = (const float*)d_in[5];
  const float* w_lat  = (const float*)d_in[6];
  const float* b_lat  = (const float*)d_in[7];
  const float* w_sm   = (const float*)d_in[8];
  const float* b_sm   = (const float*)d_in[9];
  const float* q_embed= (const float*)d_in[10];
  const float* q_pos  = (const float*)d_in[11];
  const float* Wq     = (const float*)d_in[12];
  const float* bq     = (const float*)d_in[13];
  const float* Wo     = (const float*)d_in[14];
  const float* bo     = (const float*)d_in[15];
  const float* Wp1    = (const float*)d_in[16];
  const float* bp1    = (const float*)d_in[17];
  const float* Wp2    = (const float*)d_in[18];
  const float* bp2    = (const float*)d_in[19];
  const float* w_r1   = (const float*)d_in[20];
  const float* b_r1   = (const float*)d_in[21];
  const float* w_r2   = (const float*)d_in[22];
  const float* b_r2   = (const float*)d_in[23];
  const float* w_b1   = (const float*)d_in[24];
  const float* b_b1   = (const float*)d_in[25];
  const float* w_b2   = (const float*)d_in[26];
  const float* b_b2   = (const float*)d_in[27];
  const float* w_cls  = (const float*)d_in[28];
  const float* b_cls  = (const float*)d_in[29];
  float* out = (float*)d_out;

  float* ws = (float*)d_ws;
  size_t off = 0;
  auto alloc = [&](size_t n) { float* p = ws + off; off += n; return p; };
  ushort_t* flat    = (ushort_t*)alloc(5529600);   // 4800 x 2304 bf16
  ushort_t* xcl     = (ushort_t*)alloc(1048576);   // 8192 x 256 bf16
  ushort_t* x2p     = (ushort_t*)alloc(1115136);   // 2 x 66 x 66 x 256 bf16
  ushort_t* fcl     = (ushort_t*)alloc(1048576);   // 8192 x 256 bf16
  ushort_t* wcomb   = (ushort_t*)alloc(65536);     // 256 x 512 bf16
  ushort_t* tct     = (ushort_t*)alloc(32768);     // 512 x 128 bf16
  ushort_t* win_bf  = (ushort_t*)alloc(16384);     // 256 x 128 bf16
  float*    biasc   = alloc(256);
  ushort_t* wlat_bf = (ushort_t*)alloc(32768);
  ushort_t* wsm_bf  = (ushort_t*)alloc(294912);
  ushort_t* wp1_bf  = (ushort_t*)alloc(1769472);   // 6 x 256 x 2304
  ushort_t* wqr_bf  = (ushort_t*)alloc(393216);    // 6 x 512 x 256
  float*    bqr     = alloc(3072);                 // 6 x 512
  ushort_t* wp2_bf  = (ushort_t*)alloc(196608);    // 6 x 256 x 256
  ushort_t* wo_bf   = (ushort_t*)alloc(196608);
  ushort_t* wb1_bf  = (ushort_t*)alloc(32768);
  float* queries = alloc(153600);
  ushort_t* qbf  = (ushort_t*)alloc(76800);
  float* h1      = alloc(153600);
  float* qbuf    = alloc(153600);
  float* kv      = alloc(153600);
  ushort_t* ao   = (ushort_t*)alloc(76800);
  float* hb      = alloc(153600);
  ushort_t* pvm  = (ushort_t*)alloc(76800);
  float* boxes   = alloc(2400);
  (void)ws_size; (void)in_sizes; (void)n_in; (void)out_size;

  // --- weight prep ---
  k_tc<<<256, 256, 0, stream>>>(w_tf, tct);
  k_cvt_all<<<4384, 256, 0, stream>>>(w_in, w_lat, Wp2, Wo, w_b1, Wp1,
                                      win_bf, wlat_bf, wp2_bf, wo_bf, wb1_bf, wp1_bf);
  k_bcomb<<<1, 256, 0, stream>>>(w_in, b_tf, b_in, biasc);
  // Wcomb = win_bf @ tct^T  (M=256, N=512, K=128) -> bf16 wcomb
  k_gemm_bf16<0, 6, 0><<<dim3(4, 8), 256, 0, stream>>>(win_bf, tct, nullptr, nullptr,
                                                       nullptr, wcomb, 256, 512, 128);
  k_cvt_wsm<<<2304, 256, 0, stream>>>(w_sm, wsm_bf);
  k_cvt_wqr<<<3072, 256, 0, stream>>>(w_r1, Wq, wqr_bf);
  k_bias_qr<<<12, 256, 0, stream>>>(b_r1, bq, bqr);
  k_zero<<<1089, 256, 0, stream>>>((uint4*)x2p, 278784);

  // --- backbone ---
  k_feat<<<dim3(128, 4), 256, 0, stream>>>(feat, wcomb, biasc, xcl);
  k_gemm_bf16<0, 1, 0><<<dim3(128, 4), 256, 0, stream>>>(xcl, wlat_bf, b_lat, nullptr,
                                                         nullptr, x2p, BB * HW, 256, 256);
  k_gemm128<1, 1><<<dim3(64, 4), 256, 0, stream>>>(x2p, wsm_bf, b_sm, fcl, BB * HW, KP);
  k_init<<<600, 256, 0, stream>>>(q_embed, q_pos, pb, queries, qbf, boxes);

  const int M6 = BB * NQ;                 // 600
  const int Mp = BB * NQ * NP;            // 4800
  dim3 g600((M6 + 63) / 64, 4);           // (10,4)
  dim3 g600w((M6 + 63) / 64, 8);          // (10,8) for merged N=512
  dim3 gp((Mp + 127) / 128, 4);           // (38,4)

  for (int l = 0; l < NL; ++l) {
    // merged h1 (relu) | qbuf GEMM on queries
    k_gemm_bf16<0, 4, 1><<<g600w, 256, 0, stream>>>(qbf, wqr_bf + (size_t)l * 512 * 256,
                                                    bqr + l * 512, nullptr, h1,
                                                    (ushort_t*)qbuf, M6, 512, 256);
    // fused ref-point + sampling
    k_sample<<<Mp, 256, 0, stream>>>(fcl, h1, w_r2, b_r2, boxes, flat);
    // Wp1 GEMM + fused relu+pmean -> pvm bf16 (big tile)
    k_gemm128<0, 0><<<gp, 256, 0, stream>>>(flat, wp1_bf + (size_t)l * 256 * KP,
                                            bp1 + (size_t)l * DM, pvm, Mp, KP);
    // kv = pvm @ Wp2 + bp2
    k_gemm_bf16<0, 0, 1><<<g600, 256, 0, stream>>>(pvm, wp2_bf + (size_t)l * DM * DM,
                                                   bp2 + (size_t)l * DM, nullptr, kv,
                                                   nullptr, M6, DM, DM);
    k_attn<<<M6, 256, 0, stream>>>(qbuf, kv, ao);
    // queries += ao @ Wo + bo   (fp32 master + bf16 mirror)
    k_gemm_bf16<0, 2, 1><<<g600, 256, 0, stream>>>(ao, wo_bf + (size_t)l * DM * DM,
                                                   bo + (size_t)l * DM, queries, queries,
                                                   qbf, M6, DM, DM);
    // hb = relu(queries @ w_b1 + b_b1)
    k_gemm_bf16<1, 0, 1><<<g600, 256, 0, stream>>>(qbf, wb1_bf, b_b1, nullptr, hb,
                                                   nullptr, M6, DM, DM);
    k_box<<<M6, 256, 0, stream>>>(hb, w_b2, b_b2, boxes);
  }
  k_final<<<M6, 256, 0, stream>>>(queries, w_cls, b_cls, boxes, out);
}